// Round 1
// baseline (919.469 us; speedup 1.0000x reference)
//
#include <hip/hip_runtime.h>
#include <hip/hip_bf16.h>
#include <math.h>

#define BB 64
#define NN 256
#define CCH 512

// ---------------- LayerNorm over C ----------------
__global__ __launch_bounds__(128) void ln_kernel(const float* __restrict__ x,
    const float* __restrict__ g, const float* __restrict__ bta,
    float* __restrict__ out)
{
    int r = blockIdx.x;
    const float4* xr = (const float4*)(x + (size_t)r * CCH);
    float4 v = xr[threadIdx.x];
    float s  = v.x + v.y + v.z + v.w;
    float ss = v.x*v.x + v.y*v.y + v.z*v.z + v.w*v.w;
    #pragma unroll
    for (int o = 32; o > 0; o >>= 1) {
        s  += __shfl_down(s, o);
        ss += __shfl_down(ss, o);
    }
    __shared__ float red[4];
    int wid = threadIdx.x >> 6;
    if ((threadIdx.x & 63) == 0) { red[wid] = s; red[2 + wid] = ss; }
    __syncthreads();
    s  = red[0] + red[1];
    ss = red[2] + red[3];
    float mu  = s * (1.0f / CCH);
    float var = ss * (1.0f / CCH) - mu * mu;
    float rs  = rsqrtf(var + 1e-5f);
    float4 gv = ((const float4*)g)[threadIdx.x];
    float4 bv = ((const float4*)bta)[threadIdx.x];
    float4 o;
    o.x = (v.x - mu) * rs * gv.x + bv.x;
    o.y = (v.y - mu) * rs * gv.y + bv.y;
    o.z = (v.z - mu) * rs * gv.z + bv.z;
    o.w = (v.w - mu) * rs * gv.w + bv.w;
    ((float4*)(out + (size_t)r * CCH))[threadIdx.x] = o;
}

// ---------------- fp32 tiled GEMM: C = epi(A[MxK] @ B[KxN]) ----------------
// 64x64 tile, BK=16, 256 threads, 4x4 micro-tile.
template<bool RELU, bool SCALEA, bool RES>
__global__ __launch_bounds__(256) void gemm_kernel(
    const float* __restrict__ A, const float* __restrict__ Bm,
    const float* __restrict__ bias, const float* __restrict__ scale,
    const float* __restrict__ res, float* __restrict__ Cout,
    int M, int N, int K)
{
    __shared__ float As[16][64];
    __shared__ float Bs[16][64];
    int tid = threadIdx.x;
    int tx = tid & 15, ty = tid >> 4;
    int row0 = blockIdx.y * 64;
    int col0 = blockIdx.x * 64;
    int arow = tid >> 2, ak4 = (tid & 3) * 4;
    int brow = tid >> 4, bc4 = (tid & 15) * 4;
    float acc[4][4] = {};
    float ascale = 1.0f;
    if (SCALEA) ascale = scale[row0 + arow];

    for (int k0 = 0; k0 < K; k0 += 16) {
        float4 av = *(const float4*)(A + (size_t)(row0 + arow) * K + k0 + ak4);
        if (SCALEA) { av.x *= ascale; av.y *= ascale; av.z *= ascale; av.w *= ascale; }
        float4 bv = *(const float4*)(Bm + (size_t)(k0 + brow) * N + col0 + bc4);
        As[ak4 + 0][arow] = av.x;
        As[ak4 + 1][arow] = av.y;
        As[ak4 + 2][arow] = av.z;
        As[ak4 + 3][arow] = av.w;
        *(float4*)&Bs[brow][bc4] = bv;
        __syncthreads();
        #pragma unroll
        for (int kk = 0; kk < 16; ++kk) {
            float a[4], b[4];
            *(float4*)a = *(const float4*)&As[kk][ty * 4];
            *(float4*)b = *(const float4*)&Bs[kk][tx * 4];
            #pragma unroll
            for (int i = 0; i < 4; ++i)
                #pragma unroll
                for (int j = 0; j < 4; ++j)
                    acc[i][j] += a[i] * b[j];
        }
        __syncthreads();
    }

    float4 bb = *(const float4*)(bias + col0 + tx * 4);
    #pragma unroll
    for (int i = 0; i < 4; ++i) {
        size_t row = (size_t)(row0 + ty * 4 + i);
        float o[4];
        o[0] = acc[i][0] + bb.x;
        o[1] = acc[i][1] + bb.y;
        o[2] = acc[i][2] + bb.z;
        o[3] = acc[i][3] + bb.w;
        if (RELU) {
            #pragma unroll
            for (int j = 0; j < 4; ++j) o[j] = fmaxf(o[j], 0.0f);
        }
        if (RES) {
            float4 r4 = *(const float4*)(res + row * N + col0 + tx * 4);
            o[0] += r4.x; o[1] += r4.y; o[2] += r4.z; o[3] += r4.w;
        }
        *(float4*)(Cout + row * N + col0 + tx * 4) = *(float4*)o;
    }
}

// ---------------- Wc transpose: [O=256][I=256][3] -> [I][3][O=256] ----------------
__global__ __launch_bounds__(256) void wct_kernel(const float* __restrict__ Wc,
                                                  float* __restrict__ Wct)
{
    int idx = blockIdx.x * 256 + threadIdx.x;      // < 256*3*256
    int o  = idx & 255;
    int k  = (idx >> 8) % 3;
    int i  = idx / 768;
    Wct[idx] = Wc[((size_t)o * NN + i) * 3 + k];
}

// ---------------- Conv1d over C (N channels, k=3, pad=1), shift folded in ----------------
// out[b, no, c] = sum_{ni,dc} Wc[no,ni,dc+1] * h[b,ni,c+dc-s(ni)]
//   gated by 0<=c+dc<512 (conv pad; explicit) and 0<=c+dc-s<512 (shift pad; LDS zero-fill)
__global__ __launch_bounds__(256) void conv_kernel(
    const float* __restrict__ H, const float* __restrict__ Wct,
    const float* __restrict__ bc, float* __restrict__ Y)
{
    __shared__ float Hs[16][68];        // rows: ni chunk, cols: c0-2 .. c0+65
    __shared__ float Wcs[16 * 3 * 64];  // [ni][k][no]
    int tid = threadIdx.x;
    int tx = tid & 15, ty = tid >> 4;
    int c0 = blockIdx.x * 64;
    int n0 = blockIdx.y * 64;
    int b  = blockIdx.z;
    const float* Hb = H + (size_t)b * NN * CCH;
    float acc[4][4] = {};

    for (int ni0 = 0; ni0 < NN; ni0 += 16) {
        for (int idx = tid; idx < 16 * 68; idx += 256) {
            int r = idx / 68, col = idx % 68;
            int gc = c0 - 2 + col;
            Hs[r][col] = ((unsigned)gc < (unsigned)CCH)
                       ? Hb[(size_t)(ni0 + r) * CCH + gc] : 0.0f;
        }
        for (int idx = tid; idx < 3072; idx += 256) {
            int ni  = idx / 192;
            int rem = idx % 192;
            int k   = rem >> 6;
            int no  = rem & 63;
            Wcs[idx] = Wct[((size_t)(ni0 + ni) * 3 + k) * NN + n0 + no];
        }
        __syncthreads();
        #pragma unroll 4
        for (int ni = 0; ni < 16; ++ni) {
            int ng = ni0 + ni;
            int s = (ng < 86) ? -1 : (ng < 172 ? 0 : 1);
            #pragma unroll
            for (int dc = -1; dc <= 1; ++dc) {
                float w[4];
                *(float4*)w = *(const float4*)&Wcs[(ni * 3 + (dc + 1)) * 64 + ty * 4];
                int base = tx * 4 + dc - s + 2;
                float hv[4];
                #pragma unroll
                for (int j = 0; j < 4; ++j) {
                    int cg = c0 + tx * 4 + j + dc;
                    hv[j] = ((unsigned)cg < (unsigned)CCH) ? Hs[ni][base + j] : 0.0f;
                }
                #pragma unroll
                for (int i = 0; i < 4; ++i)
                    #pragma unroll
                    for (int j = 0; j < 4; ++j)
                        acc[i][j] += w[i] * hv[j];
            }
        }
        __syncthreads();
    }

    #pragma unroll
    for (int i = 0; i < 4; ++i) {
        int no = n0 + ty * 4 + i;
        float bcv = bc[no];
        float o[4];
        #pragma unroll
        for (int j = 0; j < 4; ++j) o[j] = acc[i][j] + bcv;
        *(float4*)(Y + ((size_t)b * NN + no) * CCH + c0 + tx * 4) = *(float4*)o;
    }
}

// ---------------- row mean over C ----------------
__global__ __launch_bounds__(64) void rowmean_kernel(const float* __restrict__ Y,
                                                     float* __restrict__ se)
{
    int r = blockIdx.x;
    const float* yr = Y + (size_t)r * CCH;
    float s = 0.0f;
    #pragma unroll
    for (int i = 0; i < 8; ++i) s += yr[threadIdx.x + i * 64];
    #pragma unroll
    for (int o = 32; o > 0; o >>= 1) s += __shfl_down(s, o);
    if (threadIdx.x == 0) se[r] = s * (1.0f / CCH);
}

// ---------------- SE MLP: ex = sigmoid(relu(se@We1+be1)@We2+be2) ----------------
__global__ __launch_bounds__(256) void semlp_kernel(const float* __restrict__ se,
    const float* __restrict__ We1, const float* __restrict__ be1,
    const float* __restrict__ We2, const float* __restrict__ be2,
    float* __restrict__ ex)
{
    __shared__ float sse[256];
    __shared__ float e1[32];
    int b = blockIdx.x, t = threadIdx.x;
    sse[t] = se[b * 256 + t];
    __syncthreads();
    if (t < 32) {
        float a = be1[t];
        #pragma unroll 8
        for (int i = 0; i < 256; ++i) a += sse[i] * We1[i * 32 + t];
        e1[t] = fmaxf(a, 0.0f);
    }
    __syncthreads();
    float a = be2[t];
    #pragma unroll
    for (int j = 0; j < 32; ++j) a += e1[j] * We2[j * 256 + t];
    ex[b * 256 + t] = 1.0f / (1.0f + expf(-a));
}

extern "C" void kernel_launch(void* const* d_in, const int* in_sizes, int n_in,
                              void* d_out, int out_size, void* d_ws, size_t ws_size,
                              hipStream_t stream) {
    const float* x    = (const float*)d_in[0];
    const float* ln_g = (const float*)d_in[1];
    const float* ln_b = (const float*)d_in[2];
    const float* Ws   = (const float*)d_in[3];
    const float* bs   = (const float*)d_in[4];
    const float* Wc   = (const float*)d_in[5];
    const float* bc   = (const float*)d_in[6];
    const float* We1  = (const float*)d_in[7];
    const float* be1  = (const float*)d_in[8];
    const float* We2  = (const float*)d_in[9];
    const float* be2  = (const float*)d_in[10];
    const float* Wf1  = (const float*)d_in[11];
    const float* bf1  = (const float*)d_in[12];
    const float* Wf2  = (const float*)d_in[13];
    const float* bf2  = (const float*)d_in[14];
    float* out = (float*)d_out;
    float* ws  = (float*)d_ws;

    const size_t BNC = (size_t)BB * NN * CCH;       // 8,388,608
    float* XN   = ws;                                // [BNC], dead after gemm1
    float* Hbuf = ws + BNC;                          // [BNC], dead after conv
    float* Y    = ws;                                // reuse XN region
    float* T    = ws + BNC;                          // [2*BNC], overwrites Hbuf (dead)
    float* SE   = ws + 3 * BNC;                      // [16384]
    float* EX   = SE + 16384;                        // [16384]
    float* WCT  = EX + 16384;                        // [196608]

    wct_kernel<<<768, 256, 0, stream>>>(Wc, WCT);
    ln_kernel<<<BB * NN, 128, 0, stream>>>(x, ln_g, ln_b, XN);
    // h = relu(xn @ Ws + bs)   [16384 x 512]
    gemm_kernel<true, false, false><<<dim3(8, 256), 256, 0, stream>>>(
        XN, Ws, bs, nullptr, nullptr, Hbuf, BB * NN, CCH, CCH);
    // y = conv1d(shift(h)) + bc
    conv_kernel<<<dim3(8, 4, 64), 256, 0, stream>>>(Hbuf, WCT, bc, Y);
    // SE gate
    rowmean_kernel<<<BB * NN, 64, 0, stream>>>(Y, SE);
    semlp_kernel<<<BB, 256, 0, stream>>>(SE, We1, be1, We2, be2, EX);
    // t = relu((y * ex) @ Wf1 + bf1)   [16384 x 1024]
    gemm_kernel<true, true, false><<<dim3(16, 256), 256, 0, stream>>>(
        Y, Wf1, bf1, EX, nullptr, T, BB * NN, 2 * CCH, CCH);
    // out = t @ Wf2 + bf2 + x
    gemm_kernel<false, false, true><<<dim3(8, 256), 256, 0, stream>>>(
        T, Wf2, bf2, nullptr, x, out, BB * NN, CCH, 2 * CCH);
}

// Round 2
// 164.932 us; speedup vs baseline: 5.5748x; 5.5748x over previous
//
#include <hip/hip_runtime.h>
#include <hip/hip_bf16.h>
#include <math.h>

#define BB 64
#define NN 256
#define CCH 512

typedef unsigned short u16;
typedef __attribute__((ext_vector_type(8))) short s16x8;
typedef __attribute__((ext_vector_type(4))) float f32x4;

#define AS1 __attribute__((address_space(1)))
#define AS3 __attribute__((address_space(3)))

static __device__ __forceinline__ float b2f(u16 u) {
    union { unsigned int i; float f; } x; x.i = ((unsigned int)u) << 16; return x.f;
}
static __device__ __forceinline__ u16 f2b(float f) {
    __hip_bfloat16 h = __float2bfloat16(f);
    union { __hip_bfloat16 h; u16 u; } x; x.h = h; return x.u;
}
static __device__ __forceinline__ void gll16(const void* g, void* l) {
    __builtin_amdgcn_global_load_lds((const AS1 unsigned int*)g,
                                     (AS3 unsigned int*)l, 16, 0, 0);
}

// ---------------- LayerNorm over C -> bf16 ----------------
__global__ __launch_bounds__(128) void ln_kernel(const float* __restrict__ x,
    const float* __restrict__ g, const float* __restrict__ bta,
    u16* __restrict__ out)
{
    int r = blockIdx.x;
    const float4* xr = (const float4*)(x + (size_t)r * CCH);
    float4 v = xr[threadIdx.x];
    float s  = v.x + v.y + v.z + v.w;
    float ss = v.x*v.x + v.y*v.y + v.z*v.z + v.w*v.w;
    #pragma unroll
    for (int o = 32; o > 0; o >>= 1) {
        s  += __shfl_down(s, o);
        ss += __shfl_down(ss, o);
    }
    __shared__ float red[4];
    int wid = threadIdx.x >> 6;
    if ((threadIdx.x & 63) == 0) { red[wid] = s; red[2 + wid] = ss; }
    __syncthreads();
    s  = red[0] + red[1];
    ss = red[2] + red[3];
    float mu  = s * (1.0f / CCH);
    float var = ss * (1.0f / CCH) - mu * mu;
    float rs  = rsqrtf(var + 1e-5f);
    float4 gv = ((const float4*)g)[threadIdx.x];
    float4 bv = ((const float4*)bta)[threadIdx.x];
    ushort4 o;
    o.x = f2b((v.x - mu) * rs * gv.x + bv.x);
    o.y = f2b((v.y - mu) * rs * gv.y + bv.y);
    o.z = f2b((v.z - mu) * rs * gv.z + bv.z);
    o.w = f2b((v.w - mu) * rs * gv.w + bv.w);
    ((ushort4*)(out + (size_t)r * CCH))[threadIdx.x] = o;
}

// ---------------- weight transpose-cast: Wt[n][k] = bf16(W[k][n]) ----------------
__global__ __launch_bounds__(256) void wtc_kernel(const float* __restrict__ W,
                                                  u16* __restrict__ Wt, int K, int N)
{
    __shared__ float t[32][33];
    int n0 = blockIdx.x * 32, k0 = blockIdx.y * 32;
    int tx = threadIdx.x & 31, ty = threadIdx.x >> 5;   // 32 x 8
    #pragma unroll
    for (int i = 0; i < 4; ++i)
        t[ty + i * 8][tx] = W[(size_t)(k0 + ty + i * 8) * N + n0 + tx];
    __syncthreads();
    #pragma unroll
    for (int i = 0; i < 4; ++i)
        Wt[(size_t)(n0 + ty + i * 8) * K + k0 + tx] = f2b(t[tx][ty + i * 8]);
}

// ---------------- Wc relayout: Wc3[k][o][i] = bf16(Wc[o][i][k]) ----------------
__global__ __launch_bounds__(256) void wc3_kernel(const float* __restrict__ Wc,
                                                  u16* __restrict__ Wc3)
{
    int idx = blockIdx.x * 256 + threadIdx.x;   // < 3*256*256 = 196608
    int i = idx & 255;
    int o = (idx >> 8) & 255;
    int k = idx >> 16;
    Wc3[idx] = f2b(Wc[((size_t)o * NN + i) * 3 + k]);
}

// ---------------- shifted transpose: Hts[b][c'+1][ni] = Hs[b][ni][c'] ----------------
__global__ __launch_bounds__(256) void hts_kernel(const u16* __restrict__ H,
                                                  u16* __restrict__ Hts)
{
    __shared__ u16 t[32][33];
    int b = blockIdx.z, c0 = blockIdx.x * 32, n0 = blockIdx.y * 32;
    int tx = threadIdx.x, ty = threadIdx.y;   // 32 x 8
    const u16* Hb = H + (size_t)b * NN * CCH;
    #pragma unroll
    for (int i = 0; i < 4; ++i) {
        int ni = n0 + ty + i * 8;
        int s  = (ni < 86) ? -1 : (ni < 172 ? 0 : 1);
        int cs = c0 + tx - s;
        t[ty + i * 8][tx] = ((unsigned)cs < (unsigned)CCH) ? Hb[(size_t)ni * CCH + cs] : (u16)0;
    }
    __syncthreads();
    u16* HtsB = Hts + (size_t)b * 514 * 256;
    #pragma unroll
    for (int i = 0; i < 4; ++i) {
        int c = c0 + ty + i * 8;
        HtsB[(size_t)(c + 1) * 256 + n0 + tx] = t[tx][ty + i * 8];
    }
}

__global__ __launch_bounds__(256) void htspad_kernel(u16* __restrict__ Hts)
{
    int idx = blockIdx.x * 256 + threadIdx.x;   // < 64*2*256
    int b = idx >> 9;
    int r = ((idx >> 8) & 1) ? 513 : 0;
    int c = idx & 255;
    Hts[((size_t)b * 514 + r) * 256 + c] = 0;
}

// ---------------- bf16 MFMA BT-GEMM: out = epi(A[MxK] @ Bt[NxK]^T) ----------------
// 128x128 tile, BK=32, 4 waves, each wave 64x64 (4x4 frags of 16x16x32).
// MODE 0: relu(acc + bias[col]) -> bf16
// MODE 1: relu(acc*scale[row] + bias[col]) -> bf16
// MODE 2: acc + bias[col] + res[row][col] -> f32
template<int MODE>
__global__ __launch_bounds__(256) void gemm_bt(
    const u16* __restrict__ A, const u16* __restrict__ Bt,
    const float* __restrict__ bias, const float* __restrict__ scale,
    const float* __restrict__ res, void* __restrict__ outv,
    int M, int N, int K)
{
    __shared__ u16 As[128 * 32];
    __shared__ u16 Bs[128 * 32];
    const int tid = threadIdx.x;
    const int l   = tid & 63;
    const int w   = tid >> 6;
    const int row0 = blockIdx.y * 128;
    const int col0 = blockIdx.x * 128;

    // staging: wave w fills 1KB chunks w and w+4 of each tile (16 rows/chunk)
    const int srow = w * 16 + (l >> 2);
    const int skof = (l & 3) * 8;
    const u16* aSrc = A  + (size_t)(row0 + srow) * K + skof;
    const u16* bSrc = Bt + (size_t)(col0 + srow) * K + skof;
    u16* AsW = &As[w * 512];
    u16* BsW = &Bs[w * 512];

    const f32x4 zero = {0.0f, 0.0f, 0.0f, 0.0f};
    f32x4 acc[4][4];
    #pragma unroll
    for (int m = 0; m < 4; ++m)
        #pragma unroll
        for (int n = 0; n < 4; ++n) acc[m][n] = zero;

    const int wr = (w >> 1) * 64;
    const int wc = (w & 1) * 64;
    const int fr = l & 15;
    const int fk = (l >> 4) * 8;

    for (int k0 = 0; k0 < K; k0 += 32) {
        __syncthreads();
        gll16(aSrc + k0,                    AsW);
        gll16(aSrc + (size_t)64 * K + k0,   AsW + 2048);
        gll16(bSrc + k0,                    BsW);
        gll16(bSrc + (size_t)64 * K + k0,   BsW + 2048);
        __syncthreads();
        s16x8 af[4], bfr[4];
        #pragma unroll
        for (int m = 0; m < 4; ++m)
            af[m] = *(const s16x8*)&As[(wr + m * 16 + fr) * 32 + fk];
        #pragma unroll
        for (int n = 0; n < 4; ++n)
            bfr[n] = *(const s16x8*)&Bs[(wc + n * 16 + fr) * 32 + fk];
        #pragma unroll
        for (int m = 0; m < 4; ++m)
            #pragma unroll
            for (int n = 0; n < 4; ++n)
                acc[m][n] = __builtin_amdgcn_mfma_f32_16x16x32_bf16(af[m], bfr[n], acc[m][n], 0, 0, 0);
    }

    float bval[4];
    #pragma unroll
    for (int n = 0; n < 4; ++n) bval[n] = bias[col0 + wc + n * 16 + fr];

    #pragma unroll
    for (int m = 0; m < 4; ++m) {
        #pragma unroll
        for (int j = 0; j < 4; ++j) {
            const int row = row0 + wr + m * 16 + (l >> 4) * 4 + j;
            float sc = (MODE == 1) ? scale[row] : 1.0f;
            #pragma unroll
            for (int n = 0; n < 4; ++n) {
                const int col = col0 + wc + n * 16 + fr;
                float v = acc[m][n][j];
                if (MODE == 0) {
                    v = fmaxf(v + bval[n], 0.0f);
                    ((u16*)outv)[(size_t)row * N + col] = f2b(v);
                } else if (MODE == 1) {
                    v = fmaxf(v * sc + bval[n], 0.0f);
                    ((u16*)outv)[(size_t)row * N + col] = f2b(v);
                } else {
                    ((float*)outv)[(size_t)row * N + col] = v + bval[n] + res[(size_t)row * N + col];
                }
            }
        }
    }
}

// ---------------- conv as batched BT-GEMM over (k,ni) ----------------
// Y[b][no][c] = sum_k sum_ni Wc3[k][no][ni] * Hts[b][c+k][ni]  + bc[no]
__global__ __launch_bounds__(256) void conv_mfma(
    const u16* __restrict__ Wc3, const u16* __restrict__ Hts,
    const float* __restrict__ bc, u16* __restrict__ Y)
{
    __shared__ u16 As[128 * 32];
    __shared__ u16 Bs[128 * 32];
    const int tid = threadIdx.x;
    const int l   = tid & 63;
    const int w   = tid >> 6;
    const int b   = blockIdx.z;
    const int no0 = blockIdx.y * 128;
    const int c0  = blockIdx.x * 128;
    const u16* HtsB = Hts + (size_t)b * 514 * 256;

    const int srow = w * 16 + (l >> 2);
    const int skof = (l & 3) * 8;
    u16* AsW = &As[w * 512];
    u16* BsW = &Bs[w * 512];

    const f32x4 zero = {0.0f, 0.0f, 0.0f, 0.0f};
    f32x4 acc[4][4];
    #pragma unroll
    for (int m = 0; m < 4; ++m)
        #pragma unroll
        for (int n = 0; n < 4; ++n) acc[m][n] = zero;

    const int wr = (w >> 1) * 64;
    const int wc = (w & 1) * 64;
    const int fr = l & 15;
    const int fk = (l >> 4) * 8;

    for (int kseg = 0; kseg < 3; ++kseg) {
        const u16* aBase = Wc3 + (size_t)kseg * 65536 + (size_t)(no0 + srow) * 256 + skof;
        const u16* bBase = HtsB + (size_t)(c0 + srow + kseg) * 256 + skof;
        for (int k0 = 0; k0 < 256; k0 += 32) {
            __syncthreads();
            gll16(aBase + k0,                 AsW);
            gll16(aBase + 64 * 256 + k0,      AsW + 2048);
            gll16(bBase + k0,                 BsW);
            gll16(bBase + 64 * 256 + k0,      BsW + 2048);
            __syncthreads();
            s16x8 af[4], bfr[4];
            #pragma unroll
            for (int m = 0; m < 4; ++m)
                af[m] = *(const s16x8*)&As[(wr + m * 16 + fr) * 32 + fk];
            #pragma unroll
            for (int n = 0; n < 4; ++n)
                bfr[n] = *(const s16x8*)&Bs[(wc + n * 16 + fr) * 32 + fk];
            #pragma unroll
            for (int m = 0; m < 4; ++m)
                #pragma unroll
                for (int n = 0; n < 4; ++n)
                    acc[m][n] = __builtin_amdgcn_mfma_f32_16x16x32_bf16(af[m], bfr[n], acc[m][n], 0, 0, 0);
        }
    }

    #pragma unroll
    for (int m = 0; m < 4; ++m) {
        #pragma unroll
        for (int j = 0; j < 4; ++j) {
            const int no = no0 + wr + m * 16 + (l >> 4) * 4 + j;
            const float bcv = bc[no];
            #pragma unroll
            for (int n = 0; n < 4; ++n) {
                const int c = c0 + wc + n * 16 + fr;
                Y[((size_t)b * NN + no) * CCH + c] = f2b(acc[m][n][j] + bcv);
            }
        }
    }
}

// ---------------- row mean over C (bf16 in, f32 out) ----------------
__global__ __launch_bounds__(64) void rowmean_kernel(const u16* __restrict__ Y,
                                                     float* __restrict__ se)
{
    int r = blockIdx.x;
    const ushort4* yr = (const ushort4*)(Y + (size_t)r * CCH);
    float s = 0.0f;
    #pragma unroll
    for (int i = 0; i < 2; ++i) {
        ushort4 u = yr[threadIdx.x + i * 64];
        s += b2f(u.x) + b2f(u.y) + b2f(u.z) + b2f(u.w);
    }
    #pragma unroll
    for (int o = 32; o > 0; o >>= 1) s += __shfl_down(s, o);
    if (threadIdx.x == 0) se[r] = s * (1.0f / CCH);
}

// ---------------- SE MLP ----------------
__global__ __launch_bounds__(256) void semlp_kernel(const float* __restrict__ se,
    const float* __restrict__ We1, const float* __restrict__ be1,
    const float* __restrict__ We2, const float* __restrict__ be2,
    float* __restrict__ ex)
{
    __shared__ float sse[256];
    __shared__ float e1[32];
    int b = blockIdx.x, t = threadIdx.x;
    sse[t] = se[b * 256 + t];
    __syncthreads();
    if (t < 32) {
        float a = be1[t];
        #pragma unroll 8
        for (int i = 0; i < 256; ++i) a += sse[i] * We1[i * 32 + t];
        e1[t] = fmaxf(a, 0.0f);
    }
    __syncthreads();
    float a = be2[t];
    #pragma unroll
    for (int j = 0; j < 32; ++j) a += e1[j] * We2[j * 256 + t];
    ex[b * 256 + t] = 1.0f / (1.0f + expf(-a));
}

extern "C" void kernel_launch(void* const* d_in, const int* in_sizes, int n_in,
                              void* d_out, int out_size, void* d_ws, size_t ws_size,
                              hipStream_t stream) {
    const float* x    = (const float*)d_in[0];
    const float* ln_g = (const float*)d_in[1];
    const float* ln_b = (const float*)d_in[2];
    const float* Ws   = (const float*)d_in[3];
    const float* bs   = (const float*)d_in[4];
    const float* Wc   = (const float*)d_in[5];
    const float* bc   = (const float*)d_in[6];
    const float* We1  = (const float*)d_in[7];
    const float* be1  = (const float*)d_in[8];
    const float* We2  = (const float*)d_in[9];
    const float* be2  = (const float*)d_in[10];
    const float* Wf1  = (const float*)d_in[11];
    const float* bf1  = (const float*)d_in[12];
    const float* Wf2  = (const float*)d_in[13];
    const float* bf2  = (const float*)d_in[14];
    float* out = (float*)d_out;
    char* w8   = (char*)d_ws;

    // workspace layout (bytes)
    u16* XN  = (u16*)(w8);                          // [0, 16M)  16384x512 bf16
    u16* Y   = XN;                                  // reuse after XN dead
    u16* H   = (u16*)(w8 + (16u << 20));            // [16M, 32M)
    u16* Hts = (u16*)(w8 + (32u << 20));            // [32M, 32M+16.84M) 64x514x256
    u16* T   = (u16*)(w8 + (16u << 20));            // [16M, 48M) over H+Hts (dead)
    char* tail = w8 + 50397184;
    float* SE   = (float*)(tail);                   // 64K
    float* EX   = (float*)(tail + 65536);           // 64K
    u16* Wst    = (u16*)(tail + 131072);            // 512K  [512][512]
    u16* Wf1t   = (u16*)(tail + 655360);            // 1M    [1024][512]
    u16* Wf2t   = (u16*)(tail + 1703936);           // 1M    [512][1024]
    u16* Wc3    = (u16*)(tail + 2752512);           // 384K  [3][256][256]

    // weight prep
    wtc_kernel<<<dim3(16, 16), 256, 0, stream>>>(Ws,  Wst,  512, 512);
    wtc_kernel<<<dim3(32, 16), 256, 0, stream>>>(Wf1, Wf1t, 512, 1024);
    wtc_kernel<<<dim3(16, 32), 256, 0, stream>>>(Wf2, Wf2t, 1024, 512);
    wc3_kernel<<<768, 256, 0, stream>>>(Wc, Wc3);

    // LN -> bf16
    ln_kernel<<<BB * NN, 128, 0, stream>>>(x, ln_g, ln_b, XN);
    // H = relu(XN @ Ws + bs)
    gemm_bt<0><<<dim3(4, 128), 256, 0, stream>>>(XN, Wst, bs, nullptr, nullptr,
                                                 H, BB * NN, CCH, CCH);
    // shifted transpose + pad
    hts_kernel<<<dim3(16, 8, 64), dim3(32, 8), 0, stream>>>(H, Hts);
    htspad_kernel<<<128, 256, 0, stream>>>(Hts);
    // Y = conv1d(shift(H)) + bc
    conv_mfma<<<dim3(4, 2, 64), 256, 0, stream>>>(Wc3, Hts, bc, Y);
    // SE gate
    rowmean_kernel<<<BB * NN, 64, 0, stream>>>(Y, SE);
    semlp_kernel<<<BB, 256, 0, stream>>>(SE, We1, be1, We2, be2, EX);
    // T = relu((Y*ex) @ Wf1 + bf1)
    gemm_bt<1><<<dim3(8, 128), 256, 0, stream>>>(Y, Wf1t, bf1, EX, nullptr,
                                                 T, BB * NN, 2 * CCH, CCH);
    // out = T @ Wf2 + bf2 + x
    gemm_bt<2><<<dim3(4, 128), 256, 0, stream>>>(T, Wf2t, bf2, nullptr, x,
                                                 out, BB * NN, CCH, 2 * CCH);
}

// Round 3
// 154.611 us; speedup vs baseline: 5.9470x; 1.0668x over previous
//
#include <hip/hip_runtime.h>
#include <hip/hip_bf16.h>
#include <math.h>

#define BB 64
#define NN 256
#define CCH 512

typedef unsigned short u16;
typedef __attribute__((ext_vector_type(8))) short s16x8;
typedef __attribute__((ext_vector_type(4))) float f32x4;

#define AS1 __attribute__((address_space(1)))
#define AS3 __attribute__((address_space(3)))

static __device__ __forceinline__ float b2f(u16 u) {
    union { unsigned int i; float f; } x; x.i = ((unsigned int)u) << 16; return x.f;
}
static __device__ __forceinline__ u16 f2b(float f) {
    __hip_bfloat16 h = __float2bfloat16(f);
    union { __hip_bfloat16 h; u16 u; } x; x.h = h; return x.u;
}
static __device__ __forceinline__ void gll16(const void* g, void* l) {
    __builtin_amdgcn_global_load_lds((const AS1 unsigned int*)g,
                                     (AS3 unsigned int*)l, 16, 0, 0);
}

// ---------------- LayerNorm over C -> bf16 ----------------
__global__ __launch_bounds__(128) void ln_kernel(const float* __restrict__ x,
    const float* __restrict__ g, const float* __restrict__ bta,
    u16* __restrict__ out)
{
    int r = blockIdx.x;
    const float4* xr = (const float4*)(x + (size_t)r * CCH);
    float4 v = xr[threadIdx.x];
    float s  = v.x + v.y + v.z + v.w;
    float ss = v.x*v.x + v.y*v.y + v.z*v.z + v.w*v.w;
    #pragma unroll
    for (int o = 32; o > 0; o >>= 1) {
        s  += __shfl_down(s, o);
        ss += __shfl_down(ss, o);
    }
    __shared__ float red[4];
    int wid = threadIdx.x >> 6;
    if ((threadIdx.x & 63) == 0) { red[wid] = s; red[2 + wid] = ss; }
    __syncthreads();
    s  = red[0] + red[1];
    ss = red[2] + red[3];
    float mu  = s * (1.0f / CCH);
    float var = ss * (1.0f / CCH) - mu * mu;
    float rs  = rsqrtf(var + 1e-5f);
    float4 gv = ((const float4*)g)[threadIdx.x];
    float4 bv = ((const float4*)bta)[threadIdx.x];
    ushort4 o;
    o.x = f2b((v.x - mu) * rs * gv.x + bv.x);
    o.y = f2b((v.y - mu) * rs * gv.y + bv.y);
    o.z = f2b((v.z - mu) * rs * gv.z + bv.z);
    o.w = f2b((v.w - mu) * rs * gv.w + bv.w);
    ((ushort4*)(out + (size_t)r * CCH))[threadIdx.x] = o;
}

// ---------------- weight transpose-cast: Wt[n][k] = bf16(W[k][n]) ----------------
__global__ __launch_bounds__(256) void wtc_kernel(const float* __restrict__ W,
                                                  u16* __restrict__ Wt, int K, int N)
{
    __shared__ float t[32][33];
    int n0 = blockIdx.x * 32, k0 = blockIdx.y * 32;
    int tx = threadIdx.x & 31, ty = threadIdx.x >> 5;   // 32 x 8
    #pragma unroll
    for (int i = 0; i < 4; ++i)
        t[ty + i * 8][tx] = W[(size_t)(k0 + ty + i * 8) * N + n0 + tx];
    __syncthreads();
    #pragma unroll
    for (int i = 0; i < 4; ++i)
        Wt[(size_t)(n0 + ty + i * 8) * K + k0 + tx] = f2b(t[tx][ty + i * 8]);
}

// ---------------- Wc relayout: Wc3[k][o][i] = bf16(Wc[o][i][k]) ----------------
__global__ __launch_bounds__(256) void wc3_kernel(const float* __restrict__ Wc,
                                                  u16* __restrict__ Wc3)
{
    int idx = blockIdx.x * 256 + threadIdx.x;   // < 3*256*256 = 196608
    int i = idx & 255;
    int o = (idx >> 8) & 255;
    int k = idx >> 16;
    Wc3[idx] = f2b(Wc[((size_t)o * NN + i) * 3 + k]);
}

// ---------------- zero Hts edge rows (r in {0,1,512,513}) + SEraw ----------------
__global__ __launch_bounds__(256) void zero_kernel(u16* __restrict__ Hts,
                                                   float* __restrict__ SEraw)
{
    int idx = blockIdx.x * 256 + threadIdx.x;
    if (blockIdx.x < 256) {
        int b   = idx >> 10;
        int rem = idx & 1023;
        int rr  = rem >> 8;
        int r   = (rr & 1) + (rr >> 1) * 512;   // 0,1,512,513
        Hts[((size_t)b * 514 + r) * 256 + (rem & 255)] = 0;
    } else {
        SEraw[idx - 65536] = 0.0f;
    }
}

// ---------------- bf16 MFMA BT-GEMM, 2-phase double-buffered ----------------
// 128x128 tile, BK=32, 4 waves; XCD-chunked block swizzle (gridDim.x % 8 == 0).
// MODE 0: relu(acc + bias[col]) -> scattered write into Hts (shifted transpose)
// MODE 1: relu(acc*scale[row] + bias[col]) -> bf16
// MODE 2: acc + bias[col] + res[row][col] -> f32
template<int MODE>
__global__ __launch_bounds__(256) void gemm_bt(
    const u16* __restrict__ A, const u16* __restrict__ Bt,
    const float* __restrict__ bias, const float* __restrict__ scale,
    const float* __restrict__ res, void* __restrict__ outv,
    u16* __restrict__ Hts,
    int M, int N, int K, int ncols)
{
    __shared__ u16 As[2][128 * 32];
    __shared__ u16 Bs[2][128 * 32];
    const int tid = threadIdx.x;
    const int l   = tid & 63;
    const int w   = tid >> 6;
    const int nwg  = gridDim.x;
    const int work = (blockIdx.x & 7) * (nwg >> 3) + (blockIdx.x >> 3);
    const int row0 = (work / ncols) * 128;
    const int col0 = (work % ncols) * 128;

    const int srow = w * 16 + (l >> 2);
    const int skof = (l & 3) * 8;
    const u16* aSrc = A  + (size_t)(row0 + srow) * K + skof;
    const u16* bSrc = Bt + (size_t)(col0 + srow) * K + skof;

    const f32x4 zero = {0.0f, 0.0f, 0.0f, 0.0f};
    f32x4 acc[4][4];
    #pragma unroll
    for (int m = 0; m < 4; ++m)
        #pragma unroll
        for (int n = 0; n < 4; ++n) acc[m][n] = zero;

    const int wr = (w >> 1) * 64;
    const int wc = (w & 1) * 64;
    const int fr = l & 15;
    const int fk = (l >> 4) * 8;
    const int NT = K >> 5;

    // prologue: stage tile 0 into buf 0
    gll16(aSrc,                  &As[0][w * 512]);
    gll16(aSrc + (size_t)64 * K, &As[0][w * 512 + 2048]);
    gll16(bSrc,                  &Bs[0][w * 512]);
    gll16(bSrc + (size_t)64 * K, &Bs[0][w * 512 + 2048]);
    __syncthreads();

    int cur = 0;
    for (int t = 0; t < NT; ++t) {
        if (t + 1 < NT) {                     // stage next tile into other buf
            const int k1 = (t + 1) * 32;
            gll16(aSrc + k1,                  &As[cur ^ 1][w * 512]);
            gll16(aSrc + (size_t)64 * K + k1, &As[cur ^ 1][w * 512 + 2048]);
            gll16(bSrc + k1,                  &Bs[cur ^ 1][w * 512]);
            gll16(bSrc + (size_t)64 * K + k1, &Bs[cur ^ 1][w * 512 + 2048]);
        }
        s16x8 af[4], bf4[4];
        #pragma unroll
        for (int m = 0; m < 4; ++m)
            af[m] = *(const s16x8*)&As[cur][(wr + m * 16 + fr) * 32 + fk];
        #pragma unroll
        for (int n = 0; n < 4; ++n)
            bf4[n] = *(const s16x8*)&Bs[cur][(wc + n * 16 + fr) * 32 + fk];
        __builtin_amdgcn_s_setprio(1);
        #pragma unroll
        for (int m = 0; m < 4; ++m)
            #pragma unroll
            for (int n = 0; n < 4; ++n)
                acc[m][n] = __builtin_amdgcn_mfma_f32_16x16x32_bf16(af[m], bf4[n], acc[m][n], 0, 0, 0);
        __builtin_amdgcn_s_setprio(0);
        __syncthreads();                      // vmcnt(0)+lgkmcnt(0) drain here
        cur ^= 1;
    }

    float bval[4];
    #pragma unroll
    for (int n = 0; n < 4; ++n) bval[n] = bias[col0 + wc + n * 16 + fr];

    if (MODE == 0) {
        // write shifted transpose: Hts[b][col+1+s(ni)][ni] = relu(v)
        #pragma unroll
        for (int m = 0; m < 4; ++m) {
            const int rowb = row0 + wr + m * 16;
            u16* HtsB = Hts + (size_t)(rowb >> 8) * 514 * 256;
            #pragma unroll
            for (int j = 0; j < 4; ++j) {
                const int ni = (rowb + (l >> 4) * 4 + j) & 255;
                const int s  = (ni < 86) ? -1 : (ni < 172 ? 0 : 1);
                #pragma unroll
                for (int n = 0; n < 4; ++n) {
                    const int col = col0 + wc + n * 16 + fr;
                    float v = fmaxf(acc[m][n][j] + bval[n], 0.0f);
                    HtsB[(size_t)(col + 1 + s) * 256 + ni] = f2b(v);
                }
            }
        }
    } else {
        #pragma unroll
        for (int m = 0; m < 4; ++m) {
            #pragma unroll
            for (int j = 0; j < 4; ++j) {
                const int row = row0 + wr + m * 16 + (l >> 4) * 4 + j;
                float sc = (MODE == 1) ? scale[row] : 1.0f;
                #pragma unroll
                for (int n = 0; n < 4; ++n) {
                    const int col = col0 + wc + n * 16 + fr;
                    float v = acc[m][n][j];
                    if (MODE == 1) {
                        v = fmaxf(v * sc + bval[n], 0.0f);
                        ((u16*)outv)[(size_t)row * N + col] = f2b(v);
                    } else {
                        ((float*)outv)[(size_t)row * N + col] =
                            v + bval[n] + res[(size_t)row * N + col];
                    }
                }
            }
        }
    }
}

// ---------------- conv as batched BT-GEMM, 2-phase dbuf, SE fused ----------------
// Y[b][no][c] = sum_kseg sum_ni Wc3[kseg][no][ni] * Hts[b][c+kseg][ni] + bc[no]
// SEraw[b][no] += sum_c acc  (atomic, pre-zeroed)
__global__ __launch_bounds__(256) void conv_mfma(
    const u16* __restrict__ Wc3, const u16* __restrict__ Hts,
    const float* __restrict__ bc, u16* __restrict__ Y, float* __restrict__ SEraw)
{
    __shared__ u16 As[2][128 * 32];
    __shared__ u16 Bs[2][128 * 32];
    const int tid = threadIdx.x;
    const int l   = tid & 63;
    const int w   = tid >> 6;
    const int work = (blockIdx.x & 7) * 64 + (blockIdx.x >> 3);   // nwg = 512
    const int b    = work >> 3;
    const int no0  = ((work >> 2) & 1) * 128;
    const int c0   = (work & 3) * 128;
    const u16* HtsB = Hts + (size_t)b * 514 * 256;

    const int srow = w * 16 + (l >> 2);
    const int skof = (l & 3) * 8;
    const u16* aBase = Wc3  + (size_t)(no0 + srow) * 256 + skof;
    const u16* bBase = HtsB + (size_t)(c0  + srow) * 256 + skof;

    const f32x4 zero = {0.0f, 0.0f, 0.0f, 0.0f};
    f32x4 acc[4][4];
    #pragma unroll
    for (int m = 0; m < 4; ++m)
        #pragma unroll
        for (int n = 0; n < 4; ++n) acc[m][n] = zero;

    const int wr = (w >> 1) * 64;
    const int wc = (w & 1) * 64;
    const int fr = l & 15;
    const int fk = (l >> 4) * 8;

    // t in [0,24): kseg = t>>3, k0 = (t&7)*32
    // A offset: kseg*65536 + k0 ; B offset: kseg*256 + k0
    {
        gll16(aBase,            &As[0][w * 512]);
        gll16(aBase + 64 * 256, &As[0][w * 512 + 2048]);
        gll16(bBase,            &Bs[0][w * 512]);
        gll16(bBase + 64 * 256, &Bs[0][w * 512 + 2048]);
    }
    __syncthreads();

    int cur = 0;
    for (int t = 0; t < 24; ++t) {
        if (t + 1 < 24) {
            const int t1 = t + 1;
            const int aoff = (t1 >> 3) * 65536 + (t1 & 7) * 32;
            const int boff = (t1 >> 3) * 256   + (t1 & 7) * 32;
            gll16(aBase + aoff,            &As[cur ^ 1][w * 512]);
            gll16(aBase + aoff + 64 * 256, &As[cur ^ 1][w * 512 + 2048]);
            gll16(bBase + boff,            &Bs[cur ^ 1][w * 512]);
            gll16(bBase + boff + 64 * 256, &Bs[cur ^ 1][w * 512 + 2048]);
        }
        s16x8 af[4], bf4[4];
        #pragma unroll
        for (int m = 0; m < 4; ++m)
            af[m] = *(const s16x8*)&As[cur][(wr + m * 16 + fr) * 32 + fk];
        #pragma unroll
        for (int n = 0; n < 4; ++n)
            bf4[n] = *(const s16x8*)&Bs[cur][(wc + n * 16 + fr) * 32 + fk];
        __builtin_amdgcn_s_setprio(1);
        #pragma unroll
        for (int m = 0; m < 4; ++m)
            #pragma unroll
            for (int n = 0; n < 4; ++n)
                acc[m][n] = __builtin_amdgcn_mfma_f32_16x16x32_bf16(af[m], bf4[n], acc[m][n], 0, 0, 0);
        __builtin_amdgcn_s_setprio(0);
        __syncthreads();
        cur ^= 1;
    }

    #pragma unroll
    for (int m = 0; m < 4; ++m) {
        #pragma unroll
        for (int j = 0; j < 4; ++j) {
            const int no = no0 + wr + m * 16 + (l >> 4) * 4 + j;
            const float bcv = bc[no];
            float p = 0.0f;
            #pragma unroll
            for (int n = 0; n < 4; ++n) {
                const int c = c0 + wc + n * 16 + fr;
                float v = acc[m][n][j];
                Y[((size_t)b * NN + no) * CCH + c] = f2b(v + bcv);
                p += v;
            }
            p += __shfl_xor(p, 1);
            p += __shfl_xor(p, 2);
            p += __shfl_xor(p, 4);
            p += __shfl_xor(p, 8);
            if (fr == 0) atomicAdd(&SEraw[b * NN + no], p);
        }
    }
}

// ---------------- SE MLP: ex = sigmoid(relu(se@We1+be1)@We2+be2) ----------------
// se[b][n] = SEraw[b][n]/512 + bc[n]
__global__ __launch_bounds__(256) void semlp_kernel(const float* __restrict__ seraw,
    const float* __restrict__ bc,
    const float* __restrict__ We1, const float* __restrict__ be1,
    const float* __restrict__ We2, const float* __restrict__ be2,
    float* __restrict__ ex)
{
    __shared__ float sse[256];
    __shared__ float e1[32];
    int b = blockIdx.x, t = threadIdx.x;
    sse[t] = seraw[b * 256 + t] * (1.0f / CCH) + bc[t];
    __syncthreads();
    if (t < 32) {
        float a = be1[t];
        #pragma unroll 8
        for (int i = 0; i < 256; ++i) a += sse[i] * We1[i * 32 + t];
        e1[t] = fmaxf(a, 0.0f);
    }
    __syncthreads();
    float a = be2[t];
    #pragma unroll
    for (int j = 0; j < 32; ++j) a += e1[j] * We2[j * 256 + t];
    ex[b * 256 + t] = 1.0f / (1.0f + expf(-a));
}

extern "C" void kernel_launch(void* const* d_in, const int* in_sizes, int n_in,
                              void* d_out, int out_size, void* d_ws, size_t ws_size,
                              hipStream_t stream) {
    const float* x    = (const float*)d_in[0];
    const float* ln_g = (const float*)d_in[1];
    const float* ln_b = (const float*)d_in[2];
    const float* Ws   = (const float*)d_in[3];
    const float* bs   = (const float*)d_in[4];
    const float* Wc   = (const float*)d_in[5];
    const float* bc   = (const float*)d_in[6];
    const float* We1  = (const float*)d_in[7];
    const float* be1  = (const float*)d_in[8];
    const float* We2  = (const float*)d_in[9];
    const float* be2  = (const float*)d_in[10];
    const float* Wf1  = (const float*)d_in[11];
    const float* bf1  = (const float*)d_in[12];
    const float* Wf2  = (const float*)d_in[13];
    const float* bf2  = (const float*)d_in[14];
    float* out = (float*)d_out;
    char* w8   = (char*)d_ws;

    // workspace layout (bytes):
    //   [0, 16M)        XN (bf16 16384x512), later reused as Y
    //   [16M, ~32.9M)   Hts (bf16 64x514x256); dead after conv
    //   [16M, 48M)      T  (bf16 16384x1024) — overlays Hts after it's dead
    //   [48.06M ...]    tail: SEraw, EX, Wst, Wf1t, Wf2t, Wc3
    u16* XN  = (u16*)(w8);
    u16* Y   = XN;
    u16* Hts = (u16*)(w8 + (16u << 20));
    u16* T   = (u16*)(w8 + (16u << 20));
    char* tail = w8 + 50397184;
    float* SEraw = (float*)(tail);                  // 64K
    float* EX    = (float*)(tail + 65536);          // 64K
    u16* Wst     = (u16*)(tail + 131072);           // 512K [512][512]
    u16* Wf1t    = (u16*)(tail + 655360);           // 1M   [1024][512]
    u16* Wf2t    = (u16*)(tail + 1703936);          // 1M   [512][1024]
    u16* Wc3     = (u16*)(tail + 2752512);          // 384K [3][256][256]

    // weight prep
    wtc_kernel<<<dim3(16, 16), 256, 0, stream>>>(Ws,  Wst,  512, 512);
    wtc_kernel<<<dim3(32, 16), 256, 0, stream>>>(Wf1, Wf1t, 512, 1024);
    wtc_kernel<<<dim3(16, 32), 256, 0, stream>>>(Wf2, Wf2t, 1024, 512);
    wc3_kernel<<<768, 256, 0, stream>>>(Wc, Wc3);
    zero_kernel<<<320, 256, 0, stream>>>(Hts, SEraw);

    // LN -> bf16
    ln_kernel<<<BB * NN, 128, 0, stream>>>(x, ln_g, ln_b, XN);
    // Hts = shifted-transpose(relu(XN @ Ws + bs))
    gemm_bt<0><<<512, 256, 0, stream>>>(XN, Wst, bs, nullptr, nullptr,
                                        nullptr, Hts, BB * NN, CCH, CCH, 4);
    // Y = conv1d(shift(H)) + bc ; SEraw = row-sums
    conv_mfma<<<512, 256, 0, stream>>>(Wc3, Hts, bc, Y, SEraw);
    // ex = sigmoid(MLP(se))
    semlp_kernel<<<BB, 256, 0, stream>>>(SEraw, bc, We1, be1, We2, be2, EX);
    // T = relu((Y*ex) @ Wf1 + bf1)
    gemm_bt<1><<<1024, 256, 0, stream>>>(Y, Wf1t, bf1, EX, nullptr,
                                         T, nullptr, BB * NN, 2 * CCH, CCH, 8);
    // out = T @ Wf2 + bf2 + x
    gemm_bt<2><<<512, 256, 0, stream>>>(T, Wf2t, bf2, nullptr, x,
                                        out, nullptr, BB * NN, CCH, 2 * CCH, 4);
}

// Round 4
// 134.668 us; speedup vs baseline: 6.8276x; 1.1481x over previous
//
#include <hip/hip_runtime.h>
#include <hip/hip_bf16.h>
#include <math.h>

#define BB 64
#define NN 256
#define CCH 512

typedef unsigned short u16;
typedef __attribute__((ext_vector_type(8))) short s16x8;
typedef __attribute__((ext_vector_type(4))) float f32x4;

#define AS1 __attribute__((address_space(1)))
#define AS3 __attribute__((address_space(3)))

static __device__ __forceinline__ float b2f(u16 u) {
    union { unsigned int i; float f; } x; x.i = ((unsigned int)u) << 16; return x.f;
}
static __device__ __forceinline__ u16 f2b(float f) {
    __hip_bfloat16 h = __float2bfloat16(f);
    union { __hip_bfloat16 h; u16 u; } x; x.h = h; return x.u;
}
static __device__ __forceinline__ void gll16(const void* g, void* l) {
    __builtin_amdgcn_global_load_lds((const AS1 unsigned int*)g,
                                     (AS3 unsigned int*)l, 16, 0, 0);
}

#define VM3  asm volatile("s_waitcnt vmcnt(3)" ::: "memory")
#define VM0  asm volatile("s_waitcnt vmcnt(0)" ::: "memory")
#define MEMB asm volatile("" ::: "memory")

// ---------------- LayerNorm over C -> bf16 ----------------
__global__ __launch_bounds__(128) void ln_kernel(const float* __restrict__ x,
    const float* __restrict__ g, const float* __restrict__ bta,
    u16* __restrict__ out)
{
    int r = blockIdx.x;
    const float4* xr = (const float4*)(x + (size_t)r * CCH);
    float4 v = xr[threadIdx.x];
    float s  = v.x + v.y + v.z + v.w;
    float ss = v.x*v.x + v.y*v.y + v.z*v.z + v.w*v.w;
    #pragma unroll
    for (int o = 32; o > 0; o >>= 1) {
        s  += __shfl_down(s, o);
        ss += __shfl_down(ss, o);
    }
    __shared__ float red[4];
    int wid = threadIdx.x >> 6;
    if ((threadIdx.x & 63) == 0) { red[wid] = s; red[2 + wid] = ss; }
    __syncthreads();
    s  = red[0] + red[1];
    ss = red[2] + red[3];
    float mu  = s * (1.0f / CCH);
    float var = ss * (1.0f / CCH) - mu * mu;
    float rs  = rsqrtf(var + 1e-5f);
    float4 gv = ((const float4*)g)[threadIdx.x];
    float4 bv = ((const float4*)bta)[threadIdx.x];
    ushort4 o;
    o.x = f2b((v.x - mu) * rs * gv.x + bv.x);
    o.y = f2b((v.y - mu) * rs * gv.y + bv.y);
    o.z = f2b((v.z - mu) * rs * gv.z + bv.z);
    o.w = f2b((v.w - mu) * rs * gv.w + bv.w);
    ((ushort4*)(out + (size_t)r * CCH))[threadIdx.x] = o;
}

// ---------------- merged prep: wtc x3 + wc3 + zero ----------------
static __device__ __forceinline__ void wtc_body(const float* __restrict__ W,
    u16* __restrict__ Wt, int K, int N, int bx, int by, float* t /*[32][33]*/)
{
    int n0 = bx * 32, k0 = by * 32;
    int tx = threadIdx.x & 31, ty = threadIdx.x >> 5;
    #pragma unroll
    for (int i = 0; i < 4; ++i)
        t[(ty + i * 8) * 33 + tx] = W[(size_t)(k0 + ty + i * 8) * N + n0 + tx];
    __syncthreads();
    #pragma unroll
    for (int i = 0; i < 4; ++i)
        Wt[(size_t)(n0 + ty + i * 8) * K + k0 + tx] = f2b(t[tx * 33 + ty + i * 8]);
}

__global__ __launch_bounds__(256) void prep_kernel(
    const float* __restrict__ Ws,  u16* __restrict__ Wst,
    const float* __restrict__ Wf1, u16* __restrict__ Wf1t,
    const float* __restrict__ Wf2, u16* __restrict__ Wf2t,
    const float* __restrict__ Wc,  u16* __restrict__ Wc3,
    u16* __restrict__ Hts, float* __restrict__ SEraw)
{
    __shared__ float t[32 * 33];
    int bid = blockIdx.x;
    if (bid < 256) {                       // Ws 512x512 -> Wst
        wtc_body(Ws, Wst, 512, 512, bid & 15, bid >> 4, t);
    } else if (bid < 768) {                // Wf1 512x1024 -> Wf1t [1024][512]
        int idx = bid - 256;
        wtc_body(Wf1, Wf1t, 512, 1024, idx & 31, idx >> 5, t);
    } else if (bid < 1280) {               // Wf2 1024x512 -> Wf2t [512][1024]
        int idx = bid - 768;
        wtc_body(Wf2, Wf2t, 1024, 512, idx & 15, idx >> 4, t);
    } else if (bid < 2048) {               // Wc3[k][o][i]
        int idx = (bid - 1280) * 256 + threadIdx.x;
        int i = idx & 255;
        int o = (idx >> 8) & 255;
        int k = idx >> 16;
        Wc3[idx] = f2b(Wc[((size_t)o * NN + i) * 3 + k]);
    } else {                               // zero Hts edge rows + SEraw
        int idx = (bid - 2048) * 256 + threadIdx.x;
        if (idx < 65536) {
            int b   = idx >> 10;
            int rem = idx & 1023;
            int rr  = rem >> 8;
            int r   = (rr & 1) + (rr >> 1) * 512;   // 0,1,512,513
            Hts[((size_t)b * 514 + r) * 256 + (rem & 255)] = 0;
        } else {
            SEraw[idx - 65536] = 0.0f;
        }
    }
}

// ---------------- unified pipelined bf16 MFMA GEMM core ----------------
// BM=256, BN=128, BK=64 (2 ksubs of 32), 8 waves (512 thr), 96KB LDS,
// 2-tile double buffer, counted vmcnt(3), raw s_barrier (no drain in loop).
// MODE 0: A=Wst[c][k], B=XN[ni][k]  -> Hts shifted-transpose, relu(+bs[c=row])
// MODE 1: A=Y,  B=Wf1t -> T bf16, relu(acc*EX[row]+bf1[col])
// MODE 2: A=T,  B=Wf2t -> out f32, acc+bf2[col]+x[row][col]
// MODE 3: A=Wc3 (kseg-blocked), B=Hts rows c+kseg -> Y bf16 + SEraw atomics
template<int MODE>
__global__ __launch_bounds__(512, 1) void gemm_pipe(
    const u16* __restrict__ A, const u16* __restrict__ Bt,
    const float* __restrict__ bias, const float* __restrict__ scale,
    const float* __restrict__ res, void* __restrict__ outv,
    u16* __restrict__ auxout, float* __restrict__ SEraw)
{
    constexpr int NT = (MODE == 0) ? 8 : (MODE == 1) ? 8 : (MODE == 2) ? 16 : 12;
    constexpr int SA = (MODE == 2) ? 1024 : 512;   // A row stride (elems), MODE3 unused
    constexpr int SB = (MODE == 2) ? 1024 : 512;   // B row stride, MODE3 unused
    constexpr int NOUT = (MODE == 1) ? 1024 : 512;

    __shared__ u16 Asm[2 * 2 * 256 * 32];   // [buf][ks][256][32]  64KB
    __shared__ u16 Bsm[2 * 2 * 128 * 32];   // [buf][ks][128][32]  32KB

    const int tid = threadIdx.x;
    const int l   = tid & 63;
    const int w   = tid >> 6;
    const int nwg = gridDim.x;
    const int work = (blockIdx.x & 7) * (nwg >> 3) + (blockIdx.x >> 3);

    int row0, col0, bidx = 0;
    if (MODE == 0)      { row0 = (work >> 7) * 256; col0 = (work & 127) * 128; }
    else if (MODE == 1) { row0 = (work >> 3) * 256; col0 = (work & 7) * 128; }
    else if (MODE == 2) { row0 = (work >> 2) * 256; col0 = (work & 3) * 128; }
    else                { row0 = 0; bidx = work >> 2; col0 = (work & 3) * 128; }

    const u16* Aab  = A + (size_t)row0 * SA;                       // modes 0-2
    const u16* Bab  = Bt + (size_t)col0 * SB;                      // modes 0-2
    const u16* HtsB = Bt + (size_t)bidx * 514 * 256;               // mode 3

    const int wm = (w >> 2) * 128;
    const int wn = (w & 3) * 32;
    const int fr = l & 15;
    const int fk = (l >> 4) * 8;

    const f32x4 zero = {0.0f, 0.0f, 0.0f, 0.0f};
    f32x4 acc[8][2];
    #pragma unroll
    for (int m = 0; m < 8; ++m) { acc[m][0] = zero; acc[m][1] = zero; }

    // ---- staging helpers (pieces must issue in consumption order) ----
    auto stageA = [&](int buf, int t1, int ks) {
        u16* ald = Asm + (buf * 2 + ks) * 8192 + w * 512;
        int s = w * 64 + l;
        if (MODE == 3) {
            const int kseg = t1 >> 2, kb = (t1 & 3) * 64 + ks * 32;
            gll16(A + kseg * 65536 + (s >> 2) * 256 + kb + (s & 3) * 8, ald);
            s += 512;
            gll16(A + kseg * 65536 + (s >> 2) * 256 + kb + (s & 3) * 8, ald + 4096);
        } else {
            const int kb = t1 * 64 + ks * 32;
            gll16(Aab + (size_t)(s >> 2) * SA + kb + (s & 3) * 8, ald);
            s += 512;
            gll16(Aab + (size_t)(s >> 2) * SA + kb + (s & 3) * 8, ald + 4096);
        }
    };
    auto stageB = [&](int buf, int t1, int ks) {
        u16* bld = Bsm + (buf * 2 + ks) * 4096 + w * 512;
        const int s = tid;
        if (MODE == 3) {
            const int kseg = t1 >> 2, kb = (t1 & 3) * 64 + ks * 32;
            gll16(HtsB + (size_t)(col0 + (s >> 2) + kseg) * 256 + kb + (s & 3) * 8, bld);
        } else {
            const int kb = t1 * 64 + ks * 32;
            gll16(Bab + (size_t)(s >> 2) * SB + kb + (s & 3) * 8, bld);
        }
    };

    // ---- prologue: tile 0, pieces in order (A-ks0, B-ks0, A-ks1, B-ks1) ----
    stageA(0, 0, 0); stageB(0, 0, 0);
    stageA(0, 0, 1); stageB(0, 0, 1);

    int buf = 0;
    for (int t = 0; t < NT; ++t) {
        const bool more = (t + 1 < NT);
        #pragma unroll
        for (int ks = 0; ks < 2; ++ks) {
            if (ks == 0) { VM3; }
            else if (more) { VM3; } else { VM0; }
            __builtin_amdgcn_s_barrier();
            MEMB;
            s16x8 bf0 = *(const s16x8*)&Bsm[(buf * 2 + ks) * 4096 + (wn + 0 * 16 + fr) * 32 + fk];
            s16x8 bf1v = *(const s16x8*)&Bsm[(buf * 2 + ks) * 4096 + (wn + 1 * 16 + fr) * 32 + fk];
            s16x8 af[8];
            #pragma unroll
            for (int m = 0; m < 8; ++m)
                af[m] = *(const s16x8*)&Asm[(buf * 2 + ks) * 8192 + (wm + m * 16 + fr) * 32 + fk];
            if (more) { stageA(buf ^ 1, t + 1, ks); stageB(buf ^ 1, t + 1, ks); }
            __builtin_amdgcn_s_setprio(1);
            #pragma unroll
            for (int m = 0; m < 8; ++m) {
                acc[m][0] = __builtin_amdgcn_mfma_f32_16x16x32_bf16(af[m], bf0,  acc[m][0], 0, 0, 0);
                acc[m][1] = __builtin_amdgcn_mfma_f32_16x16x32_bf16(af[m], bf1v, acc[m][1], 0, 0, 0);
            }
            __builtin_amdgcn_s_setprio(0);
        }
        buf ^= 1;
    }

    // ---- epilogues ----
    if (MODE == 0) {
        // out rows = c, cols = (b,ni); write Hts[b][c+1+s(ni)][ni] = relu(acc+bs[c])
        #pragma unroll
        for (int m = 0; m < 8; ++m) {
            #pragma unroll
            for (int j = 0; j < 4; ++j) {
                const int c = row0 + wm + m * 16 + (l >> 4) * 4 + j;
                const float bsv = bias[c];
                #pragma unroll
                for (int n = 0; n < 2; ++n) {
                    const int gcol = col0 + wn + n * 16 + fr;
                    const int b  = gcol >> 8;
                    const int ni = gcol & 255;
                    const int s  = (ni < 86) ? -1 : (ni < 172 ? 0 : 1);
                    auxout[((size_t)b * 514 + c + 1 + s) * 256 + ni] =
                        f2b(fmaxf(acc[m][n][j] + bsv, 0.0f));
                }
            }
        }
    } else if (MODE == 1) {
        #pragma unroll
        for (int m = 0; m < 8; ++m) {
            #pragma unroll
            for (int j = 0; j < 4; ++j) {
                const int row = row0 + wm + m * 16 + (l >> 4) * 4 + j;
                const float sc = scale[row];
                #pragma unroll
                for (int n = 0; n < 2; ++n) {
                    const int col = col0 + wn + n * 16 + fr;
                    ((u16*)outv)[(size_t)row * NOUT + col] =
                        f2b(fmaxf(acc[m][n][j] * sc + bias[col], 0.0f));
                }
            }
        }
    } else if (MODE == 2) {
        #pragma unroll
        for (int m = 0; m < 8; ++m) {
            #pragma unroll
            for (int j = 0; j < 4; ++j) {
                const int row = row0 + wm + m * 16 + (l >> 4) * 4 + j;
                #pragma unroll
                for (int n = 0; n < 2; ++n) {
                    const int col = col0 + wn + n * 16 + fr;
                    ((float*)outv)[(size_t)row * NOUT + col] =
                        acc[m][n][j] + bias[col] + res[(size_t)row * NOUT + col];
                }
            }
        }
    } else {
        // conv: rows = no, cols = c; Y[b][no][c] + SE row-sum atomics
        #pragma unroll
        for (int m = 0; m < 8; ++m) {
            #pragma unroll
            for (int j = 0; j < 4; ++j) {
                const int no = wm + m * 16 + (l >> 4) * 4 + j;
                const float bcv = bias[no];
                float p = 0.0f;
                #pragma unroll
                for (int n = 0; n < 2; ++n) {
                    const int c = col0 + wn + n * 16 + fr;
                    float v = acc[m][n][j];
                    auxout[((size_t)bidx * NN + no) * CCH + c] = f2b(v + bcv);
                    p += v;
                }
                p += __shfl_xor(p, 1);
                p += __shfl_xor(p, 2);
                p += __shfl_xor(p, 4);
                p += __shfl_xor(p, 8);
                if (fr == 0) atomicAdd(&SEraw[bidx * NN + no], p);
            }
        }
    }
}

// ---------------- SE MLP: ex = sigmoid(relu(se@We1+be1)@We2+be2) ----------------
__global__ __launch_bounds__(256) void semlp_kernel(const float* __restrict__ seraw,
    const float* __restrict__ bc,
    const float* __restrict__ We1, const float* __restrict__ be1,
    const float* __restrict__ We2, const float* __restrict__ be2,
    float* __restrict__ ex)
{
    __shared__ float sse[256];
    __shared__ float e1[32];
    int b = blockIdx.x, t = threadIdx.x;
    sse[t] = seraw[b * 256 + t] * (1.0f / CCH) + bc[t];
    __syncthreads();
    if (t < 32) {
        float a = be1[t];
        #pragma unroll 8
        for (int i = 0; i < 256; ++i) a += sse[i] * We1[i * 32 + t];
        e1[t] = fmaxf(a, 0.0f);
    }
    __syncthreads();
    float a = be2[t];
    #pragma unroll
    for (int j = 0; j < 32; ++j) a += e1[j] * We2[j * 256 + t];
    ex[b * 256 + t] = 1.0f / (1.0f + expf(-a));
}

extern "C" void kernel_launch(void* const* d_in, const int* in_sizes, int n_in,
                              void* d_out, int out_size, void* d_ws, size_t ws_size,
                              hipStream_t stream) {
    const float* x    = (const float*)d_in[0];
    const float* ln_g = (const float*)d_in[1];
    const float* ln_b = (const float*)d_in[2];
    const float* Ws   = (const float*)d_in[3];
    const float* bs   = (const float*)d_in[4];
    const float* Wc   = (const float*)d_in[5];
    const float* bc   = (const float*)d_in[6];
    const float* We1  = (const float*)d_in[7];
    const float* be1  = (const float*)d_in[8];
    const float* We2  = (const float*)d_in[9];
    const float* be2  = (const float*)d_in[10];
    const float* Wf1  = (const float*)d_in[11];
    const float* bf1  = (const float*)d_in[12];
    const float* Wf2  = (const float*)d_in[13];
    const float* bf2  = (const float*)d_in[14];
    float* out = (float*)d_out;
    char* w8   = (char*)d_ws;

    // workspace:
    //   [0,16M)      XN bf16 16384x512, reused as Y after gemm0
    //   [16M,~33M)   Hts bf16 64x514x256 (dead after conv)
    //   [16M,48M)    T bf16 16384x1024 (overlays Hts)
    //   [48.06M..]   tail: SEraw, EX, Wst, Wf1t, Wf2t, Wc3
    u16* XN  = (u16*)(w8);
    u16* Y   = XN;
    u16* Hts = (u16*)(w8 + (16u << 20));
    u16* T   = (u16*)(w8 + (16u << 20));
    char* tail = w8 + 50397184;
    float* SEraw = (float*)(tail);
    float* EX    = (float*)(tail + 65536);
    u16* Wst     = (u16*)(tail + 131072);
    u16* Wf1t    = (u16*)(tail + 655360);
    u16* Wf2t    = (u16*)(tail + 1703936);
    u16* Wc3     = (u16*)(tail + 2752512);

    prep_kernel<<<2368, 256, 0, stream>>>(Ws, Wst, Wf1, Wf1t, Wf2, Wf2t,
                                          Wc, Wc3, Hts, SEraw);
    ln_kernel<<<BB * NN, 128, 0, stream>>>(x, ln_g, ln_b, XN);
    // Hts = shifted-transpose(relu(Ws^T-rows @ XN-rows + bs))   [A=Wst, B=XN]
    gemm_pipe<0><<<256, 512, 0, stream>>>(Wst, XN, bs, nullptr, nullptr,
                                          nullptr, Hts, nullptr);
    // Y = conv1d(shift(H)) + bc ; SEraw row-sums
    gemm_pipe<3><<<256, 512, 0, stream>>>(Wc3, Hts, bc, nullptr, nullptr,
                                          nullptr, Y, SEraw);
    semlp_kernel<<<BB, 256, 0, stream>>>(SEraw, bc, We1, be1, We2, be2, EX);
    // T = relu((Y*ex) @ Wf1 + bf1)
    gemm_pipe<1><<<512, 512, 0, stream>>>(Y, Wf1t, bf1, EX, nullptr,
                                          T, nullptr, nullptr);
    // out = T @ Wf2 + bf2 + x
    gemm_pipe<2><<<256, 512, 0, stream>>>(T, Wf2t, bf2, nullptr, x,
                                          out, nullptr, nullptr);
}

// Round 5
// 129.525 us; speedup vs baseline: 7.0988x; 1.0397x over previous
//
#include <hip/hip_runtime.h>
#include <hip/hip_bf16.h>
#include <math.h>

#define BB 64
#define NN 256
#define CCH 512

typedef unsigned short u16;
typedef __attribute__((ext_vector_type(8))) short s16x8;
typedef __attribute__((ext_vector_type(4))) float f32x4;

#define AS1 __attribute__((address_space(1)))
#define AS3 __attribute__((address_space(3)))

static __device__ __forceinline__ float b2f(u16 u) {
    union { unsigned int i; float f; } x; x.i = ((unsigned int)u) << 16; return x.f;
}
static __device__ __forceinline__ u16 f2b(float f) {
    __hip_bfloat16 h = __float2bfloat16(f);
    union { __hip_bfloat16 h; u16 u; } x; x.h = h; return x.u;
}
static __device__ __forceinline__ void gll16(const void* g, void* l) {
    __builtin_amdgcn_global_load_lds((const AS1 unsigned int*)g,
                                     (AS3 unsigned int*)l, 16, 0, 0);
}

#define VM6  asm volatile("s_waitcnt vmcnt(6)" ::: "memory")
#define VM3  asm volatile("s_waitcnt vmcnt(3)" ::: "memory")
#define VM0  asm volatile("s_waitcnt vmcnt(0)" ::: "memory")
#define MEMB asm volatile("" ::: "memory")

// ---------------- LayerNorm over C -> bf16 (one wave per row) ----------------
__global__ __launch_bounds__(256) void ln_kernel(const float* __restrict__ x,
    const float* __restrict__ g, const float* __restrict__ bta,
    u16* __restrict__ out)
{
    const int l = threadIdx.x & 63;
    const int r = blockIdx.x * 4 + (threadIdx.x >> 6);
    const float4* xr = (const float4*)(x + (size_t)r * CCH);
    float4 v1 = xr[l];
    float4 v2 = xr[l + 64];
    float s  = v1.x + v1.y + v1.z + v1.w + v2.x + v2.y + v2.z + v2.w;
    float ss = v1.x*v1.x + v1.y*v1.y + v1.z*v1.z + v1.w*v1.w
             + v2.x*v2.x + v2.y*v2.y + v2.z*v2.z + v2.w*v2.w;
    #pragma unroll
    for (int o = 32; o > 0; o >>= 1) {
        s  += __shfl_xor(s, o);
        ss += __shfl_xor(ss, o);
    }
    float mu  = s * (1.0f / CCH);
    float var = ss * (1.0f / CCH) - mu * mu;
    float rs  = rsqrtf(var + 1e-5f);
    float4 g1 = ((const float4*)g)[l],      g2 = ((const float4*)g)[l + 64];
    float4 b1 = ((const float4*)bta)[l],    b2 = ((const float4*)bta)[l + 64];
    ushort4 o1, o2;
    o1.x = f2b((v1.x - mu) * rs * g1.x + b1.x);
    o1.y = f2b((v1.y - mu) * rs * g1.y + b1.y);
    o1.z = f2b((v1.z - mu) * rs * g1.z + b1.z);
    o1.w = f2b((v1.w - mu) * rs * g1.w + b1.w);
    o2.x = f2b((v2.x - mu) * rs * g2.x + b2.x);
    o2.y = f2b((v2.y - mu) * rs * g2.y + b2.y);
    o2.z = f2b((v2.z - mu) * rs * g2.z + b2.z);
    o2.w = f2b((v2.w - mu) * rs * g2.w + b2.w);
    ushort4* orow = (ushort4*)(out + (size_t)r * CCH);
    orow[l]      = o1;
    orow[l + 64] = o2;
}

// ---------------- merged prep: wtc x3 + wc3 + zero ----------------
static __device__ __forceinline__ void wtc_body(const float* __restrict__ W,
    u16* __restrict__ Wt, int K, int N, int bx, int by, float* t /*[32][33]*/)
{
    int n0 = bx * 32, k0 = by * 32;
    int tx = threadIdx.x & 31, ty = threadIdx.x >> 5;
    #pragma unroll
    for (int i = 0; i < 4; ++i)
        t[(ty + i * 8) * 33 + tx] = W[(size_t)(k0 + ty + i * 8) * N + n0 + tx];
    __syncthreads();
    #pragma unroll
    for (int i = 0; i < 4; ++i)
        Wt[(size_t)(n0 + ty + i * 8) * K + k0 + tx] = f2b(t[tx * 33 + ty + i * 8]);
}

__global__ __launch_bounds__(256) void prep_kernel(
    const float* __restrict__ Ws,  u16* __restrict__ Wst,
    const float* __restrict__ Wf1, u16* __restrict__ Wf1t,
    const float* __restrict__ Wf2, u16* __restrict__ Wf2t,
    const float* __restrict__ Wc,  u16* __restrict__ Wc3,
    u16* __restrict__ Hts, float* __restrict__ SEraw)
{
    __shared__ float t[32 * 33];
    int bid = blockIdx.x;
    if (bid < 256) {                       // Ws 512x512 -> Wst
        wtc_body(Ws, Wst, 512, 512, bid & 15, bid >> 4, t);
    } else if (bid < 768) {                // Wf1 512x1024 -> Wf1t [1024][512]
        int idx = bid - 256;
        wtc_body(Wf1, Wf1t, 512, 1024, idx & 31, idx >> 5, t);
    } else if (bid < 1280) {               // Wf2 1024x512 -> Wf2t [512][1024]
        int idx = bid - 768;
        wtc_body(Wf2, Wf2t, 1024, 512, idx & 15, idx >> 4, t);
    } else if (bid < 2048) {               // Wc3[k][o][i]
        int idx = (bid - 1280) * 256 + threadIdx.x;
        int i = idx & 255;
        int o = (idx >> 8) & 255;
        int k = idx >> 16;
        Wc3[idx] = f2b(Wc[((size_t)o * NN + i) * 3 + k]);
    } else {                               // zero Hts edge rows + SEraw
        int idx = (bid - 2048) * 256 + threadIdx.x;
        if (idx < 65536) {
            int b   = idx >> 10;
            int rem = idx & 1023;
            int rr  = rem >> 8;
            int r   = (rr & 1) + (rr >> 1) * 512;   // 0,1,512,513
            Hts[((size_t)b * 514 + r) * 256 + (rem & 255)] = 0;
        } else {
            SEraw[idx - 65536] = 0.0f;
        }
    }
}

// ---------------- unified pipelined bf16 MFMA GEMM core ----------------
// BM=256, BN=128, 8 waves (512 thr). K processed as NK ksubs of 32, staged
// into a 4-slot LDS ring (96KB), 3 ksubs in flight (counted vmcnt(6), T4),
// one raw s_barrier per ksub. LDS bank-conflict fix (T2): k-chunk slot is
// XOR-swizzled with (row>>1)&3 via pre-swizzled GLOBAL source (G21), LDS
// linear for global_load_lds; frag reads apply the same XOR.
// MODE 0: A=Wst[c][k], B=XN[ni][k]  -> Hts shifted-transpose, relu(+bs[c=row])
// MODE 1: A=Y,  B=Wf1t -> T bf16, relu(acc*EX[row]+bf1[col])
// MODE 2: A=T,  B=Wf2t -> out f32, acc+bf2[col]+x[row][col]
// MODE 3: A=Wc3 (kseg-blocked), B=Hts rows c+kseg -> Y bf16 + SEraw atomics
template<int MODE>
__global__ __launch_bounds__(512, 1) void gemm_pipe(
    const u16* __restrict__ A, const u16* __restrict__ Bt,
    const float* __restrict__ bias, const float* __restrict__ scale,
    const float* __restrict__ res, void* __restrict__ outv,
    u16* __restrict__ auxout, float* __restrict__ SEraw)
{
    constexpr int NK = (MODE == 2) ? 32 : (MODE == 3) ? 24 : 16;
    constexpr int SA = (MODE == 2) ? 1024 : 512;
    constexpr int SB = (MODE == 2) ? 1024 : 512;
    constexpr int NOUT = (MODE == 1) ? 1024 : 512;

    __shared__ u16 Asm[4 * 256 * 32];   // 4 ksub slots, 64KB
    __shared__ u16 Bsm[4 * 128 * 32];   // 32KB

    const int tid = threadIdx.x;
    const int l   = tid & 63;
    const int w   = tid >> 6;
    const int nwg = gridDim.x;
    const int work = (blockIdx.x & 7) * (nwg >> 3) + (blockIdx.x >> 3);

    int row0, col0, bidx = 0;
    if (MODE == 0)      { row0 = (work >> 7) * 256; col0 = (work & 127) * 128; }
    else if (MODE == 1) { row0 = (work >> 3) * 256; col0 = (work & 7) * 128; }
    else if (MODE == 2) { row0 = (work >> 2) * 256; col0 = (work & 3) * 128; }
    else                { row0 = 0; bidx = work >> 2; col0 = (work & 3) * 128; }

    const u16* Aab  = A + (size_t)row0 * SA;                       // modes 0-2
    const u16* Bab  = Bt + (size_t)col0 * SB;                      // modes 0-2
    const u16* HtsB = Bt + (size_t)bidx * 514 * 256;               // mode 3

    const int wm = (w >> 2) * 128;
    const int wn = (w & 3) * 32;
    const int fr = l & 15;
    const int q  = l >> 4;
    const int kofs = ((q ^ ((l >> 1) & 3)) * 8);   // swizzled 16B slot for reads

    const f32x4 zero = {0.0f, 0.0f, 0.0f, 0.0f};
    f32x4 acc[8][2];
    #pragma unroll
    for (int m = 0; m < 8; ++m) { acc[m][0] = zero; acc[m][1] = zero; }

    // staging: thread s covers (row = s>>2 [+128 for A], 16B slot s&3);
    // global k-chunk pre-swizzled so LDS slot (s&3) holds chunk (s&3)^((s>>3)&3).
    const int kc0 = ((tid & 3) ^ ((tid >> 3) & 3)) * 8;
    const int srow = tid >> 2;

    auto stage = [&](int u) {
        const int slot = u & 3;
        u16* ald = Asm + slot * 8192 + w * 512;
        u16* bld = Bsm + slot * 4096 + w * 512;
        if (MODE == 3) {
            const int kseg = u >> 3, kb = (u & 7) * 32 + kc0;
            gll16(A + kseg * 65536 + srow * 256 + kb, ald);
            gll16(A + kseg * 65536 + (srow + 128) * 256 + kb, ald + 4096);
            gll16(HtsB + (size_t)(col0 + srow + kseg) * 256 + kb, bld);
        } else {
            const int kb = u * 32 + kc0;
            gll16(Aab + (size_t)srow * SA + kb, ald);
            gll16(Aab + (size_t)(srow + 128) * SA + kb, ald + 4096);
            gll16(Bab + (size_t)srow * SB + kb, bld);
        }
    };

    stage(0); stage(1); stage(2);

    for (int u = 0; u < NK; ++u) {
        if (u < NK - 2)       { VM6; }
        else if (u == NK - 2) { VM3; }
        else                  { VM0; }
        __builtin_amdgcn_s_barrier();
        MEMB;
        const int slot = u & 3;
        s16x8 bf0  = *(const s16x8*)&Bsm[slot * 4096 + (wn + fr) * 32 + kofs];
        s16x8 bf1v = *(const s16x8*)&Bsm[slot * 4096 + (wn + 16 + fr) * 32 + kofs];
        s16x8 af[8];
        #pragma unroll
        for (int m = 0; m < 8; ++m)
            af[m] = *(const s16x8*)&Asm[slot * 8192 + (wm + m * 16 + fr) * 32 + kofs];
        if (u + 3 < NK) stage(u + 3);
        __builtin_amdgcn_s_setprio(1);
        #pragma unroll
        for (int m = 0; m < 8; ++m) {
            acc[m][0] = __builtin_amdgcn_mfma_f32_16x16x32_bf16(af[m], bf0,  acc[m][0], 0, 0, 0);
            acc[m][1] = __builtin_amdgcn_mfma_f32_16x16x32_bf16(af[m], bf1v, acc[m][1], 0, 0, 0);
        }
        __builtin_amdgcn_s_setprio(0);
        MEMB;
    }

    // ---- epilogues ----
    if (MODE == 0) {
        // out rows = c, cols = (b,ni); write Hts[b][c+1+s(ni)][ni] = relu(acc+bs[c])
        #pragma unroll
        for (int m = 0; m < 8; ++m) {
            #pragma unroll
            for (int j = 0; j < 4; ++j) {
                const int c = row0 + wm + m * 16 + (l >> 4) * 4 + j;
                const float bsv = bias[c];
                #pragma unroll
                for (int n = 0; n < 2; ++n) {
                    const int gcol = col0 + wn + n * 16 + fr;
                    const int b  = gcol >> 8;
                    const int ni = gcol & 255;
                    const int s  = (ni < 86) ? -1 : (ni < 172 ? 0 : 1);
                    auxout[((size_t)b * 514 + c + 1 + s) * 256 + ni] =
                        f2b(fmaxf(acc[m][n][j] + bsv, 0.0f));
                }
            }
        }
    } else if (MODE == 1) {
        #pragma unroll
        for (int m = 0; m < 8; ++m) {
            #pragma unroll
            for (int j = 0; j < 4; ++j) {
                const int row = row0 + wm + m * 16 + (l >> 4) * 4 + j;
                const float sc = scale[row];
                #pragma unroll
                for (int n = 0; n < 2; ++n) {
                    const int col = col0 + wn + n * 16 + fr;
                    ((u16*)outv)[(size_t)row * NOUT + col] =
                        f2b(fmaxf(acc[m][n][j] * sc + bias[col], 0.0f));
                }
            }
        }
    } else if (MODE == 2) {
        #pragma unroll
        for (int m = 0; m < 8; ++m) {
            #pragma unroll
            for (int j = 0; j < 4; ++j) {
                const int row = row0 + wm + m * 16 + (l >> 4) * 4 + j;
                #pragma unroll
                for (int n = 0; n < 2; ++n) {
                    const int col = col0 + wn + n * 16 + fr;
                    ((float*)outv)[(size_t)row * NOUT + col] =
                        acc[m][n][j] + bias[col] + res[(size_t)row * NOUT + col];
                }
            }
        }
    } else {
        // conv: rows = no, cols = c; Y[b][no][c] + SE row-sum atomics
        #pragma unroll
        for (int m = 0; m < 8; ++m) {
            #pragma unroll
            for (int j = 0; j < 4; ++j) {
                const int no = wm + m * 16 + (l >> 4) * 4 + j;
                const float bcv = bias[no];
                float p = 0.0f;
                #pragma unroll
                for (int n = 0; n < 2; ++n) {
                    const int c = col0 + wn + n * 16 + fr;
                    float v = acc[m][n][j];
                    auxout[((size_t)bidx * NN + no) * CCH + c] = f2b(v + bcv);
                    p += v;
                }
                p += __shfl_xor(p, 1);
                p += __shfl_xor(p, 2);
                p += __shfl_xor(p, 4);
                p += __shfl_xor(p, 8);
                if (fr == 0) atomicAdd(&SEraw[bidx * NN + no], p);
            }
        }
    }
}

// ---------------- SE MLP: ex = sigmoid(relu(se@We1+be1)@We2+be2) ----------------
__global__ __launch_bounds__(256) void semlp_kernel(const float* __restrict__ seraw,
    const float* __restrict__ bc,
    const float* __restrict__ We1, const float* __restrict__ be1,
    const float* __restrict__ We2, const float* __restrict__ be2,
    float* __restrict__ ex)
{
    __shared__ float sse[256];
    __shared__ float e1[32];
    int b = blockIdx.x, t = threadIdx.x;
    sse[t] = seraw[b * 256 + t] * (1.0f / CCH) + bc[t];
    __syncthreads();
    if (t < 32) {
        float a = be1[t];
        #pragma unroll 8
        for (int i = 0; i < 256; ++i) a += sse[i] * We1[i * 32 + t];
        e1[t] = fmaxf(a, 0.0f);
    }
    __syncthreads();
    float a = be2[t];
    #pragma unroll
    for (int j = 0; j < 32; ++j) a += e1[j] * We2[j * 256 + t];
    ex[b * 256 + t] = 1.0f / (1.0f + expf(-a));
}

extern "C" void kernel_launch(void* const* d_in, const int* in_sizes, int n_in,
                              void* d_out, int out_size, void* d_ws, size_t ws_size,
                              hipStream_t stream) {
    const float* x    = (const float*)d_in[0];
    const float* ln_g = (const float*)d_in[1];
    const float* ln_b = (const float*)d_in[2];
    const float* Ws   = (const float*)d_in[3];
    const float* bs   = (const float*)d_in[4];
    const float* Wc   = (const float*)d_in[5];
    const float* bc   = (const float*)d_in[6];
    const float* We1  = (const float*)d_in[7];
    const float* be1  = (const float*)d_in[8];
    const float* We2  = (const float*)d_in[9];
    const float* be2  = (const float*)d_in[10];
    const float* Wf1  = (const float*)d_in[11];
    const float* bf1  = (const float*)d_in[12];
    const float* Wf2  = (const float*)d_in[13];
    const float* bf2  = (const float*)d_in[14];
    float* out = (float*)d_out;
    char* w8   = (char*)d_ws;

    // workspace:
    //   [0,16M)      XN bf16 16384x512, reused as Y after gemm0
    //   [16M,~33M)   Hts bf16 64x514x256 (dead after conv)
    //   [16M,48M)    T bf16 16384x1024 (overlays Hts)
    //   [48.06M..]   tail: SEraw, EX, Wst, Wf1t, Wf2t, Wc3
    u16* XN  = (u16*)(w8);
    u16* Y   = XN;
    u16* Hts = (u16*)(w8 + (16u << 20));
    u16* T   = (u16*)(w8 + (16u << 20));
    char* tail = w8 + 50397184;
    float* SEraw = (float*)(tail);
    float* EX    = (float*)(tail + 65536);
    u16* Wst     = (u16*)(tail + 131072);
    u16* Wf1t    = (u16*)(tail + 655360);
    u16* Wf2t    = (u16*)(tail + 1703936);
    u16* Wc3     = (u16*)(tail + 2752512);

    prep_kernel<<<2368, 256, 0, stream>>>(Ws, Wst, Wf1, Wf1t, Wf2, Wf2t,
                                          Wc, Wc3, Hts, SEraw);
    ln_kernel<<<BB * NN / 4, 256, 0, stream>>>(x, ln_g, ln_b, XN);
    // Hts = shifted-transpose(relu(Ws^T-rows @ XN-rows + bs))   [A=Wst, B=XN]
    gemm_pipe<0><<<256, 512, 0, stream>>>(Wst, XN, bs, nullptr, nullptr,
                                          nullptr, Hts, nullptr);
    // Y = conv1d(shift(H)) + bc ; SEraw row-sums
    gemm_pipe<3><<<256, 512, 0, stream>>>(Wc3, Hts, bc, nullptr, nullptr,
                                          nullptr, Y, SEraw);
    semlp_kernel<<<BB, 256, 0, stream>>>(SEraw, bc, We1, be1, We2, be2, EX);
    // T = relu((Y*ex) @ Wf1 + bf1)
    gemm_pipe<1><<<512, 512, 0, stream>>>(Y, Wf1t, bf1, EX, nullptr,
                                          T, nullptr, nullptr);
    // out = T @ Wf2 + bf2 + x
    gemm_pipe<2><<<256, 512, 0, stream>>>(T, Wf2t, bf2, nullptr, x,
                                          out, nullptr, nullptr);
}

// Round 6
// 115.350 us; speedup vs baseline: 7.9711x; 1.1229x over previous
//
#include <hip/hip_runtime.h>
#include <hip/hip_bf16.h>
#include <math.h>

#define BB 64
#define NN 256
#define CCH 512

typedef unsigned short u16;
typedef __attribute__((ext_vector_type(8))) short s16x8;
typedef __attribute__((ext_vector_type(4))) float f32x4;

#define AS1 __attribute__((address_space(1)))
#define AS3 __attribute__((address_space(3)))

static __device__ __forceinline__ u16 f2b(float f) {
    __hip_bfloat16 h = __float2bfloat16(f);
    union { __hip_bfloat16 h; u16 u; } x; x.h = h; return x.u;
}
static __device__ __forceinline__ void gll16(const void* g, void* l) {
    __builtin_amdgcn_global_load_lds((const AS1 unsigned int*)g,
                                     (AS3 unsigned int*)l, 16, 0, 0);
}

#define VM8  asm volatile("s_waitcnt vmcnt(8)" ::: "memory")
#define VM6  asm volatile("s_waitcnt vmcnt(6)" ::: "memory")
#define VM4  asm volatile("s_waitcnt vmcnt(4)" ::: "memory")
#define VM3  asm volatile("s_waitcnt vmcnt(3)" ::: "memory")
#define VM0  asm volatile("s_waitcnt vmcnt(0)" ::: "memory")
#define MEMB asm volatile("" ::: "memory")

// ---------------- merged prep (weights, Hts edges) + LayerNorm ----------------
static __device__ __forceinline__ void wtc_body(const float* __restrict__ W,
    u16* __restrict__ Wt, int K, int N, int bx, int by, float* t /*[32][33]*/)
{
    int n0 = bx * 32, k0 = by * 32;
    int tx = threadIdx.x & 31, ty = threadIdx.x >> 5;
    #pragma unroll
    for (int i = 0; i < 4; ++i)
        t[(ty + i * 8) * 33 + tx] = W[(size_t)(k0 + ty + i * 8) * N + n0 + tx];
    __syncthreads();
    #pragma unroll
    for (int i = 0; i < 4; ++i)
        Wt[(size_t)(n0 + ty + i * 8) * K + k0 + tx] = f2b(t[tx * 33 + ty + i * 8]);
}

__global__ __launch_bounds__(256) void prep_ln_kernel(
    const float* __restrict__ Ws,  u16* __restrict__ Wst,
    const float* __restrict__ Wf1, u16* __restrict__ Wf1t,
    const float* __restrict__ Wf2, u16* __restrict__ Wf2t,
    const float* __restrict__ Wc,  u16* __restrict__ Wc3,
    u16* __restrict__ Hts,
    const float* __restrict__ x, const float* __restrict__ g,
    const float* __restrict__ bta, u16* __restrict__ xnorm)
{
    __shared__ float t[32 * 33];
    int bid = blockIdx.x;
    if (bid < 256) {                       // Ws 512x512 -> Wst
        wtc_body(Ws, Wst, 512, 512, bid & 15, bid >> 4, t);
    } else if (bid < 768) {                // Wf1 512x1024 -> Wf1t [1024][512]
        int idx = bid - 256;
        wtc_body(Wf1, Wf1t, 512, 1024, idx & 31, idx >> 5, t);
    } else if (bid < 1280) {               // Wf2 1024x512 -> Wf2t [512][1024]
        int idx = bid - 768;
        wtc_body(Wf2, Wf2t, 1024, 512, idx & 15, idx >> 4, t);
    } else if (bid < 2048) {               // Wc3[k][o][i]
        int idx = (bid - 1280) * 256 + threadIdx.x;
        int i = idx & 255;
        int o = (idx >> 8) & 255;
        int k = idx >> 16;
        Wc3[idx] = f2b(Wc[((size_t)o * NN + i) * 3 + k]);
    } else if (bid < 2304) {               // zero Hts edge rows {0,1,512,513}
        int idx = (bid - 2048) * 256 + threadIdx.x;
        int b   = idx >> 10;
        int rem = idx & 1023;
        int rr  = rem >> 8;
        int r   = (rr & 1) + (rr >> 1) * 512;
        Hts[((size_t)b * 514 + r) * 256 + (rem & 255)] = 0;
    } else {                               // LayerNorm, one wave per row
        const int l = threadIdx.x & 63;
        const int r = (bid - 2304) * 4 + (threadIdx.x >> 6);
        const float4* xr = (const float4*)(x + (size_t)r * CCH);
        float4 v1 = xr[l];
        float4 v2 = xr[l + 64];
        float s  = v1.x + v1.y + v1.z + v1.w + v2.x + v2.y + v2.z + v2.w;
        float ss = v1.x*v1.x + v1.y*v1.y + v1.z*v1.z + v1.w*v1.w
                 + v2.x*v2.x + v2.y*v2.y + v2.z*v2.z + v2.w*v2.w;
        #pragma unroll
        for (int o = 32; o > 0; o >>= 1) {
            s  += __shfl_xor(s, o);
            ss += __shfl_xor(ss, o);
        }
        float mu  = s * (1.0f / CCH);
        float var = ss * (1.0f / CCH) - mu * mu;
        float rs  = rsqrtf(var + 1e-5f);
        float4 g1 = ((const float4*)g)[l],   g2 = ((const float4*)g)[l + 64];
        float4 b1 = ((const float4*)bta)[l], b2 = ((const float4*)bta)[l + 64];
        ushort4 o1, o2;
        o1.x = f2b((v1.x - mu) * rs * g1.x + b1.x);
        o1.y = f2b((v1.y - mu) * rs * g1.y + b1.y);
        o1.z = f2b((v1.z - mu) * rs * g1.z + b1.z);
        o1.w = f2b((v1.w - mu) * rs * g1.w + b1.w);
        o2.x = f2b((v2.x - mu) * rs * g2.x + b2.x);
        o2.y = f2b((v2.y - mu) * rs * g2.y + b2.y);
        o2.z = f2b((v2.z - mu) * rs * g2.z + b2.z);
        o2.w = f2b((v2.w - mu) * rs * g2.w + b2.w);
        ushort4* orow = (ushort4*)(xnorm + (size_t)r * CCH);
        orow[l]      = o1;
        orow[l + 64] = o2;
    }
}

// ---------------- unified pipelined bf16 MFMA GEMM core ----------------
// BM=256, BN=BNT (128 or 256), 8 waves (512 thr). K in ksubs of 32, 4-slot
// LDS ring, 3 ksubs in flight (counted vmcnt, T4), one raw s_barrier/ksub.
// T2 bank-conflict fix via pre-swizzled global source (G21), LDS linear.
// MODE 0: A=Wst[c][k], B=XN[ni][k]  -> Hts shifted-transpose, relu(+bs[c=row])
// MODE 1 (BNT=256): A=Y, B=Wf1t -> T bf16, relu(acc*EX[row]+bf1[col])
// MODE 2: A=T,  B=Wf2t -> out f32, acc+bf2[col]+x[row][col]
// MODE 3: A=Wc3 (kseg-blocked), B=Hts rows c+kseg -> Y bf16 + SEpart sums
template<int MODE, int BNT>
__global__ __launch_bounds__(512, 1) void gemm_pipe(
    const u16* __restrict__ A, const u16* __restrict__ Bt,
    const float* __restrict__ bias, const float* __restrict__ scale,
    const float* __restrict__ res, void* __restrict__ outv,
    u16* __restrict__ auxout, float* __restrict__ SEpart)
{
    constexpr int NK = (MODE == 2) ? 32 : (MODE == 3) ? 24 : 16;
    constexpr int SA = (MODE == 2) ? 1024 : 512;
    constexpr int SB = (MODE == 2) ? 1024 : 512;
    constexpr int NOUT = (MODE == 1) ? 1024 : 512;
    constexpr int NF = BNT / 64;            // B frags per wave
    constexpr int BSZ = BNT * 32;           // B slot elems

    __shared__ u16 Asm[4 * 256 * 32];       // 64KB
    __shared__ u16 Bsm[4 * BSZ];            // 32KB or 64KB

    const int tid = threadIdx.x;
    const int l   = tid & 63;
    const int w   = tid >> 6;
    const int nwg = gridDim.x;
    const int work = (blockIdx.x & 7) * (nwg >> 3) + (blockIdx.x >> 3);

    int row0, col0, bidx = 0;
    if (MODE == 0)      { row0 = (work >> 7) * 256; col0 = (work & 127) * 128; }
    else if (MODE == 1) { row0 = (work >> 2) * 256; col0 = (work & 3) * 256; }
    else if (MODE == 2) { row0 = (work >> 2) * 256; col0 = (work & 3) * 128; }
    else                { row0 = 0; bidx = work >> 2; col0 = (work & 3) * 128; }

    const u16* Aab  = A + (size_t)row0 * SA;                       // modes 0-2
    const u16* Bab  = Bt + (size_t)col0 * SB;                      // modes 0-2
    const u16* HtsB = Bt + (size_t)bidx * 514 * 256;               // mode 3

    const int wm = (w >> 2) * 128;
    const int wn = (w & 3) * (BNT / 4);
    const int fr = l & 15;
    const int q  = l >> 4;
    const int kofs = ((q ^ ((l >> 1) & 3)) * 8);   // swizzled 16B slot for reads

    const f32x4 zero = {0.0f, 0.0f, 0.0f, 0.0f};
    f32x4 acc[8][NF];
    #pragma unroll
    for (int m = 0; m < 8; ++m)
        #pragma unroll
        for (int n = 0; n < NF; ++n) acc[m][n] = zero;

    // staging: thread s covers (row = s>>2 [+128 for hi], 16B slot s&3);
    // global k-chunk pre-swizzled so LDS slot (s&3) holds chunk (s&3)^((s>>3)&3).
    const int kc0 = ((tid & 3) ^ ((tid >> 3) & 3)) * 8;
    const int srow = tid >> 2;

    auto stage = [&](int u) {
        const int slot = u & 3;
        u16* ald = Asm + slot * 8192 + w * 512;
        u16* bld = Bsm + slot * BSZ + w * 512;
        if (MODE == 3) {
            const int kseg = u >> 3, kb = (u & 7) * 32 + kc0;
            gll16(A + kseg * 65536 + srow * 256 + kb, ald);
            gll16(A + kseg * 65536 + (srow + 128) * 256 + kb, ald + 4096);
            gll16(HtsB + (size_t)(col0 + srow + kseg) * 256 + kb, bld);
        } else {
            const int kb = u * 32 + kc0;
            gll16(Aab + (size_t)srow * SA + kb, ald);
            gll16(Aab + (size_t)(srow + 128) * SA + kb, ald + 4096);
            gll16(Bab + (size_t)srow * SB + kb, bld);
            if (BNT == 256)
                gll16(Bab + (size_t)(srow + 128) * SB + kb, bld + 4096);
        }
    };

    stage(0); stage(1); stage(2);

    for (int u = 0; u < NK; ++u) {
        if (BNT == 128) {
            if (u < NK - 2)       { VM6; }
            else if (u == NK - 2) { VM3; }
            else                  { VM0; }
        } else {
            if (u < NK - 2)       { VM8; }
            else if (u == NK - 2) { VM4; }
            else                  { VM0; }
        }
        __builtin_amdgcn_s_barrier();
        MEMB;
        const int slot = u & 3;
        s16x8 bfv[NF];
        #pragma unroll
        for (int n = 0; n < NF; ++n)
            bfv[n] = *(const s16x8*)&Bsm[slot * BSZ + (wn + n * 16 + fr) * 32 + kofs];
        s16x8 af[8];
        #pragma unroll
        for (int m = 0; m < 8; ++m)
            af[m] = *(const s16x8*)&Asm[slot * 8192 + (wm + m * 16 + fr) * 32 + kofs];
        if (u + 3 < NK) stage(u + 3);
        __builtin_amdgcn_s_setprio(1);
        #pragma unroll
        for (int m = 0; m < 8; ++m)
            #pragma unroll
            for (int n = 0; n < NF; ++n)
                acc[m][n] = __builtin_amdgcn_mfma_f32_16x16x32_bf16(af[m], bfv[n], acc[m][n], 0, 0, 0);
        __builtin_amdgcn_s_setprio(0);
        MEMB;
    }

    // ---- epilogues ----
    if (MODE == 0) {
        // out rows = c, cols = (b,ni); write Hts[b][c+1+s(ni)][ni] = relu(acc+bs[c])
        #pragma unroll
        for (int m = 0; m < 8; ++m) {
            #pragma unroll
            for (int j = 0; j < 4; ++j) {
                const int c = row0 + wm + m * 16 + (l >> 4) * 4 + j;
                const float bsv = bias[c];
                #pragma unroll
                for (int n = 0; n < NF; ++n) {
                    const int gcol = col0 + wn + n * 16 + fr;
                    const int b  = gcol >> 8;
                    const int ni = gcol & 255;
                    const int s  = (ni < 86) ? -1 : (ni < 172 ? 0 : 1);
                    auxout[((size_t)b * 514 + c + 1 + s) * 256 + ni] =
                        f2b(fmaxf(acc[m][n][j] + bsv, 0.0f));
                }
            }
        }
    } else if (MODE == 1) {
        #pragma unroll
        for (int m = 0; m < 8; ++m) {
            #pragma unroll
            for (int j = 0; j < 4; ++j) {
                const int row = row0 + wm + m * 16 + (l >> 4) * 4 + j;
                const float sc = scale[row];
                #pragma unroll
                for (int n = 0; n < NF; ++n) {
                    const int col = col0 + wn + n * 16 + fr;
                    ((u16*)outv)[(size_t)row * NOUT + col] =
                        f2b(fmaxf(acc[m][n][j] * sc + bias[col], 0.0f));
                }
            }
        }
    } else if (MODE == 2) {
        #pragma unroll
        for (int m = 0; m < 8; ++m) {
            #pragma unroll
            for (int j = 0; j < 4; ++j) {
                const int row = row0 + wm + m * 16 + (l >> 4) * 4 + j;
                #pragma unroll
                for (int n = 0; n < NF; ++n) {
                    const int col = col0 + wn + n * 16 + fr;
                    ((float*)outv)[(size_t)row * NOUT + col] =
                        acc[m][n][j] + bias[col] + res[(size_t)row * NOUT + col];
                }
            }
        }
    } else {
        // conv: rows = no, cols = c; Y[b][no][c]; per-coltile SE partial sums
        const int ct = col0 >> 7;
        #pragma unroll
        for (int m = 0; m < 8; ++m) {
            #pragma unroll
            for (int j = 0; j < 4; ++j) {
                const int no = wm + m * 16 + (l >> 4) * 4 + j;
                const float bcv = bias[no];
                float p = 0.0f;
                #pragma unroll
                for (int n = 0; n < NF; ++n) {
                    const int c = col0 + wn + n * 16 + fr;
                    float v = acc[m][n][j];
                    auxout[((size_t)bidx * NN + no) * CCH + c] = f2b(v + bcv);
                    p += v;
                }
                p += __shfl_xor(p, 1);
                p += __shfl_xor(p, 2);
                p += __shfl_xor(p, 4);
                p += __shfl_xor(p, 8);
                if (fr == 0)
                    SEpart[ct * 16384 + bidx * NN + no] = p;
            }
        }
    }
}

// ---------------- SE MLP: ex = sigmoid(relu(se@We1+be1)@We2+be2) ----------------
// se[b][n] = (sum_ct SEpart[ct][b][n])/512 + bc[n]
__global__ __launch_bounds__(256) void semlp_kernel(const float* __restrict__ sep,
    const float* __restrict__ bc,
    const float* __restrict__ We1, const float* __restrict__ be1,
    const float* __restrict__ We2, const float* __restrict__ be2,
    float* __restrict__ ex)
{
    __shared__ float sse[256];
    __shared__ float e1[32];
    int b = blockIdx.x, t = threadIdx.x;
    int o = b * 256 + t;
    sse[t] = (sep[o] + sep[16384 + o] + sep[32768 + o] + sep[49152 + o])
             * (1.0f / CCH) + bc[t];
    __syncthreads();
    if (t < 32) {
        float a = be1[t];
        #pragma unroll 8
        for (int i = 0; i < 256; ++i) a += sse[i] * We1[i * 32 + t];
        e1[t] = fmaxf(a, 0.0f);
    }
    __syncthreads();
    float a = be2[t];
    #pragma unroll
    for (int j = 0; j < 32; ++j) a += e1[j] * We2[j * 256 + t];
    ex[b * 256 + t] = 1.0f / (1.0f + expf(-a));
}

extern "C" void kernel_launch(void* const* d_in, const int* in_sizes, int n_in,
                              void* d_out, int out_size, void* d_ws, size_t ws_size,
                              hipStream_t stream) {
    const float* x    = (const float*)d_in[0];
    const float* ln_g = (const float*)d_in[1];
    const float* ln_b = (const float*)d_in[2];
    const float* Ws   = (const float*)d_in[3];
    const float* bs   = (const float*)d_in[4];
    const float* Wc   = (const float*)d_in[5];
    const float* bc   = (const float*)d_in[6];
    const float* We1  = (const float*)d_in[7];
    const float* be1  = (const float*)d_in[8];
    const float* We2  = (const float*)d_in[9];
    const float* be2  = (const float*)d_in[10];
    const float* Wf1  = (const float*)d_in[11];
    const float* bf1  = (const float*)d_in[12];
    const float* Wf2  = (const float*)d_in[13];
    const float* bf2  = (const float*)d_in[14];
    float* out = (float*)d_out;
    char* w8   = (char*)d_ws;

    // workspace:
    //   [0,16M)      XN bf16 16384x512, reused as Y after gemm0
    //   [16M,~33M)   Hts bf16 64x514x256 (dead after conv)
    //   [16M,48M)    T bf16 16384x1024 (overlays Hts)
    //   [48.06M..]   tail: SEpart, EX, Wst, Wf1t, Wf2t, Wc3
    u16* XN  = (u16*)(w8);
    u16* Y   = XN;
    u16* Hts = (u16*)(w8 + (16u << 20));
    u16* T   = (u16*)(w8 + (16u << 20));
    char* tail = w8 + 50397184;
    float* SEpart = (float*)(tail);                 // 256K  [4][64][256]
    float* EX     = (float*)(tail + 262144);        // 64K
    u16* Wst      = (u16*)(tail + 327680);          // 512K [512][512]
    u16* Wf1t     = (u16*)(tail + 851968);          // 1M   [1024][512]
    u16* Wf2t     = (u16*)(tail + 1900544);         // 1M   [512][1024]
    u16* Wc3      = (u16*)(tail + 2949120);         // 384K [3][256][256]

    prep_ln_kernel<<<6400, 256, 0, stream>>>(Ws, Wst, Wf1, Wf1t, Wf2, Wf2t,
                                             Wc, Wc3, Hts, x, ln_g, ln_b, XN);
    // Hts = shifted-transpose(relu(Ws^T-rows @ XN-rows + bs))   [A=Wst, B=XN]
    gemm_pipe<0, 128><<<256, 512, 0, stream>>>(Wst, XN, bs, nullptr, nullptr,
                                               nullptr, Hts, nullptr);
    // Y = conv1d(shift(H)) + bc ; SEpart partial row-sums
    gemm_pipe<3, 128><<<256, 512, 0, stream>>>(Wc3, Hts, bc, nullptr, nullptr,
                                               nullptr, Y, SEpart);
    semlp_kernel<<<BB, 256, 0, stream>>>(SEpart, bc, We1, be1, We2, be2, EX);
    // T = relu((Y*ex) @ Wf1 + bf1)   [256x256 tile]
    gemm_pipe<1, 256><<<256, 512, 0, stream>>>(Y, Wf1t, bf1, EX, nullptr,
                                               T, nullptr, nullptr);
    // out = T @ Wf2 + bf2 + x
    gemm_pipe<2, 128><<<256, 512, 0, stream>>>(T, Wf2t, bf2, nullptr, x,
                                               out, nullptr, nullptr);
}